// Round 11
// baseline (223.569 us; speedup 1.0000x reference)
//
#include <hip/hip_runtime.h>
#include <hip/hip_bf16.h>
#include <type_traits>

// SelfAttention fused block, MI355X/gfx950.
// R20: diagnostic split + consolidation. P2 (dual GEMM) split into two
//      dispatches (qk: 1024 blocks, vt: 512 blocks) via the verified
//      gemm_bt_kernel wrapper — if qk-GEMM > ~48us it surfaces in the
//      top-5 with full counters (the inferred ~100us P2 cost vs the
//      ~20us cycle model is a 5x discrepancy that must be measured
//      before the next structural bet). P5 back to 128x64 (R16 best-
//      total config). Flash = R17-exact (best measured 47.8us).
//      R14 lifetime-disjoint workspace map. 6 launches.

typedef __hip_bfloat16 bf16;
typedef __attribute__((ext_vector_type(8))) short bf16x8;
typedef __attribute__((ext_vector_type(4))) float f32x4;

#define MFMA_BF16(a, b, c) __builtin_amdgcn_mfma_f32_16x16x32_bf16((a), (b), (c), 0, 0, 0)

__device__ __forceinline__ float us2f(unsigned short u) {
  unsigned int v = ((unsigned int)u) << 16;
  return __builtin_bit_cast(float, v);
}

__device__ __forceinline__ unsigned pack_bf16x2(float a, float b) {  // RNE (epilogues)
  union { __hip_bfloat162 h; unsigned u; } cv;
  cv.h = __float22bfloat162_rn(float2{a, b});
  return cv.u;
}

__device__ __forceinline__ unsigned pack_bf16x2_trunc(float a, float b) {  // 1x v_perm
  return __builtin_amdgcn_perm(__builtin_bit_cast(unsigned, b),
                               __builtin_bit_cast(unsigned, a), 0x07060302u);
}

// async global->LDS, 16B per lane; lane i's dest = wave-uniform base + i*16
__device__ __forceinline__ void gl_lds16(const bf16* g, bf16* l) {
  __builtin_amdgcn_global_load_lds(
      (const __attribute__((address_space(1))) void*)g,
      (__attribute__((address_space(3))) void*)l, 16, 0, 0);
}

// raw barrier + compile-time scheduling fence: nothing (esp. plain LDS
// loads) may move across this sync point in either direction.
__device__ __forceinline__ void barrier_pinned() {
  __builtin_amdgcn_s_barrier();
  __builtin_amdgcn_sched_barrier(0);
}

// m204 bijective XCD swizzle; requires nwg % 8 == 0.
__device__ __forceinline__ int xcd_swz(int orig, int nwg) {
  return (orig & 7) * (nwg >> 3) + (orig >> 3);
}

// ---------------- LayerNorm row core (one 256-thread block per row) ----------------
template <typename TIN>
__device__ __forceinline__ void ln_core(
    const TIN* __restrict__ in, const float* __restrict__ gamma,
    const float* __restrict__ beta, bf16* __restrict__ out,
    int stride, int D, float sc, int row, float* red)
{
  const int t = threadIdx.x;
  float x0, x1, x2, x3;
  if constexpr (std::is_same_v<TIN, float>) {
    float4 u = *(const float4*)(in + (size_t)row * stride + t * 4);
    x0 = u.x; x1 = u.y; x2 = u.z; x3 = u.w;
  } else {
    ushort4 u = *(const ushort4*)(in + (size_t)row * stride + t * 4);
    x0 = us2f(u.x); x1 = us2f(u.y); x2 = us2f(u.z); x3 = us2f(u.w);
  }
  float s = x0 + x1 + x2 + x3;
  float s2 = x0 * x0 + x1 * x1 + x2 * x2 + x3 * x3;
#pragma unroll
  for (int m = 1; m < 64; m <<= 1) {
    s += __shfl_xor(s, m);
    s2 += __shfl_xor(s2, m);
  }
  const int w = t >> 6, lane = t & 63;
  if (lane == 0) { red[w] = s; red[4 + w] = s2; }
  __syncthreads();
  if (t == 0) {
    float S = red[0] + red[1] + red[2] + red[3];
    float S2 = red[4] + red[5] + red[6] + red[7];
    float mu = S / (float)D;
    float var = S2 / (float)D - mu * mu;
    red[8] = mu;
    red[9] = rsqrtf(var + 1e-5f);
  }
  __syncthreads();
  const float mu = red[8], rs = red[9];
  float4 g4 = *(const float4*)(gamma + t * 4);
  float4 b4 = *(const float4*)(beta + t * 4);
  uint2 o;
  o.x = pack_bf16x2(((x0 - mu) * rs * g4.x + b4.x) * sc, ((x1 - mu) * rs * g4.y + b4.y) * sc);
  o.y = pack_bf16x2(((x2 - mu) * rs * g4.z + b4.z) * sc, ((x3 - mu) * rs * g4.w + b4.w) * sc);
  *(uint2*)(out + (size_t)row * D + t * 4) = o;
}

// ---------------- standalone LN pair (P3) ----------------
template <typename TIN>
__global__ __launch_bounds__(256) void ln2_kernel(
    const TIN* __restrict__ in0, const TIN* __restrict__ in1, int stride,
    const float* __restrict__ g0, const float* __restrict__ b0,
    const float* __restrict__ g1, const float* __restrict__ b1,
    bf16* __restrict__ out0, bf16* __restrict__ out1, int D,
    float sc0, float sc1)
{
  __shared__ float red[10];
  const int which = blockIdx.y;
  ln_core<TIN>(which ? in1 : in0, which ? g1 : g0, which ? b1 : b0,
               which ? out1 : out0, stride, D, which ? sc1 : sc0,
               blockIdx.x, red);
}

// ---------------- 64x64 f32->bf16 transpose tile core ----------------
__device__ __forceinline__ void transpose_core(
    const float* __restrict__ in, bf16* __restrict__ out, int C,
    int r0, int c0, float (*tile)[68])
{
  const int R = 1024;
  const int t = threadIdx.x;
  const int lr = t >> 2, lc = (t & 3) * 16;
  const float* src = in + (size_t)(r0 + lr) * C + (c0 + lc);
#pragma unroll
  for (int i = 0; i < 4; ++i) {
    float4 u = *(const float4*)(src + i * 4);
    tile[lr][lc + i * 4 + 0] = u.x;
    tile[lr][lc + i * 4 + 1] = u.y;
    tile[lr][lc + i * 4 + 2] = u.z;
    tile[lr][lc + i * 4 + 3] = u.w;
  }
  __syncthreads();
  __align__(16) bf16 tmp[16];
#pragma unroll
  for (int j = 0; j < 16; ++j) tmp[j] = __float2bfloat16(tile[lc + j][lr]);
  bf16* dst = out + (size_t)(c0 + lr) * R + (r0 + lc);
  *(bf16x8*)dst       = *(const bf16x8*)&tmp[0];
  *(bf16x8*)(dst + 8) = *(const bf16x8*)&tmp[8];
}

// ---------------- prep: input LNs (8192 blocks) + 3 weight transposes (1024 blocks) ----------------
__global__ __launch_bounds__(256) void prep_kernel(
    const float* __restrict__ keys, const float* __restrict__ values,
    const float* __restrict__ qk_g, const float* __restrict__ qk_b,
    const float* __restrict__ val_g, const float* __restrict__ val_b,
    bf16* __restrict__ keys_ln, bf16* __restrict__ values_ln,
    const float* __restrict__ w_qk, bf16* __restrict__ wqkT,
    const float* __restrict__ w_v, bf16* __restrict__ wvT,
    const float* __restrict__ w_out, bf16* __restrict__ woutT)
{
  __shared__ float tile[64][68];
  __shared__ float red[10];
  const int bid = blockIdx.x;
  if (bid < 8192) {
    const int row = bid >> 1, which = bid & 1;
    ln_core<float>(which ? values : keys, which ? val_g : qk_g,
                   which ? val_b : qk_b, which ? values_ln : keys_ln,
                   1024, 1024, 1.0f, row, red);
  } else {
    const int tz = bid - 8192;
    if (tz < 512) {
      transpose_core(w_qk, wqkT, 2048, (tz >> 5) * 64, (tz & 31) * 64, tile);
    } else if (tz < 768) {
      const int s = tz - 512;
      transpose_core(w_v, wvT, 1024, (s >> 4) * 64, (s & 15) * 64, tile);
    } else {
      const int s = tz - 768;
      transpose_core(w_out, woutT, 1024, (s >> 4) * 64, (s & 15) * 64, tile);
    }
  }
}

// ---------------- GEMM core: C(M,N) = A(M,K) @ Bt(N,K)^T (+bias), bf16 in, fp32 accum ----------------
// BK=64, double-buffered K-loop with counted vmcnt (ASL+BSL loads stay in
// flight across the compute phase). XOR chunk swizzle (c ^ (row&7)) on
// 128B LDS rows -> conflict-free ds_read_b128 frags. 2x2 waves. All raw
// barriers are sched_barrier(0)-pinned so frag ds_reads cannot hoist into
// the staging/vmcnt window. TMODE 1: coalesced vt store via LDS bounce:
// vt[((row>>11)*1024 + col)*2048 + (row&2047)].
template <int BM, int BN, int TMODE, typename TOUT>
__device__ __forceinline__ void gemm_core(
    const bf16* __restrict__ A, const bf16* __restrict__ Bt,
    const float* __restrict__ bias, TOUT* __restrict__ C,
    int N, int K, int has_bias, int bx, int by, bf16* smem)
{
  constexpr int MT = BM / 32, NT = BN / 32;     // 16x16 frags per wave
  constexpr int ASL = BM / 32, BSL = BN / 32;   // 16B staging slots per thread (BK=64)
  constexpr int BUFE = (BM + BN) * 64;          // elements per buffer
  const int t = threadIdx.x;
  const int w = t >> 6, lane = t & 63, l15 = lane & 15, quad = lane >> 4;
  const int wy = w >> 1, wx = w & 1;
  const bf16* Ab = A + (size_t)by * BM * K;
  const bf16* Bb = Bt + (size_t)bx * BN * K;
  f32x4 acc[MT][NT] = {};

  // per-thread staging sources, hoisted out of the K-loop (addr-mul once)
  const bf16* aptr[ASL];
  const bf16* bptr[BSL];
#pragma unroll
  for (int i = 0; i < ASL; ++i) {
    int s = i * 256 + t, row = s >> 3, c = (s & 7) ^ (row & 7);
    aptr[i] = Ab + (size_t)row * K + (c << 3);
  }
#pragma unroll
  for (int i = 0; i < BSL; ++i) {
    int s = i * 256 + t, row = s >> 3, c = (s & 7) ^ (row & 7);
    bptr[i] = Bb + (size_t)row * K + (c << 3);
  }

  auto stage = [&](bf16* buf, int kc) {
#pragma unroll
    for (int i = 0; i < ASL; ++i)
      gl_lds16(aptr[i] + kc, buf + (i * 256 + t) * 8);
#pragma unroll
    for (int i = 0; i < BSL; ++i)
      gl_lds16(bptr[i] + kc, buf + BM * 64 + (i * 256 + t) * 8);
  };

  const int sw = (quad ^ (l15 & 7)) << 3;
  const int NK = K >> 6;

  stage(smem, 0);  // prologue: tile 0 into buf 0

  for (int kt = 0; kt < NK; ++kt) {
    const int cur = kt & 1;
    bf16* lA = smem + cur * BUFE;
    bf16* lB = lA + BM * 64;
    barrier_pinned();  // all waves done reading buf cur^1
    if (kt + 1 < NK) {
      stage(smem + (cur ^ 1) * BUFE, (kt + 1) << 6);
      if constexpr (ASL + BSL == 8)
        asm volatile("s_waitcnt vmcnt(8)" ::: "memory");  // tile kt landed; kt+1 in flight
      else if constexpr (ASL + BSL == 6)
        asm volatile("s_waitcnt vmcnt(6)" ::: "memory");
      else
        asm volatile("s_waitcnt vmcnt(4)" ::: "memory");
    } else {
      asm volatile("s_waitcnt vmcnt(0)" ::: "memory");
    }
    barrier_pinned();  // staged data visible to all waves; reads pinned below

#pragma unroll
    for (int h = 0; h < 2; ++h) {
      const int so = sw ^ (h << 5);
      bf16x8 af[MT], bfr[NT];
#pragma unroll
      for (int mt = 0; mt < MT; ++mt)
        af[mt] = *(const bf16x8*)&lA[(wy * (BM / 2) + mt * 16 + l15) * 64 + so];
#pragma unroll
      for (int nt = 0; nt < NT; ++nt)
        bfr[nt] = *(const bf16x8*)&lB[(wx * (BN / 2) + nt * 16 + l15) * 64 + so];
#pragma unroll
      for (int mt = 0; mt < MT; ++mt)
#pragma unroll
        for (int nt = 0; nt < NT; ++nt)
          acc[mt][nt] = MFMA_BF16(af[mt], bfr[nt], acc[mt][nt]);
    }
  }

  if constexpr (TMODE == 1) {
    // acc: row n = wy*(BM/2)+mt*16+quad*4+r, col d = wx*(BN/2)+nt*16+l15 -> lOut[d][n]
    constexpr int STR = BM + 8;   // keeps d*STR*2 bytes 16B-aligned
    static_assert(BN * STR <= 2 * BUFE, "lOut must fit staging buffers");
    bf16* lOut = smem;            // aliases dead staging buffers
    __syncthreads();
#pragma unroll
    for (int mt = 0; mt < MT; ++mt)
#pragma unroll
      for (int nt = 0; nt < NT; ++nt) {
        const int d = wx * (BN / 2) + nt * 16 + l15;
        const int n = wy * (BM / 2) + mt * 16 + quad * 4;
        uint2 pk;
        pk.x = pack_bf16x2(acc[mt][nt][0], acc[mt][nt][1]);
        pk.y = pack_bf16x2(acc[mt][nt][2], acc[mt][nt][3]);
        *(uint2*)&lOut[d * STR + n] = pk;
      }
    __syncthreads();
    const int row0 = by * BM;
    const int bidx = row0 >> 11, n0 = row0 & 2047;
    const int col0 = bx * BN;
    constexpr int CPR = BM / 32;                  // 32-el chunks per d-row
    constexpr int NITER = (BN * CPR) / 256;
#pragma unroll
    for (int it = 0; it < NITER; ++it) {
      const int idx = it * 256 + t;
      const int d = idx / CPR, off = (idx % CPR) * 32;
      const bf16* srcp = &lOut[d * STR + off];
      bf16* g = (bf16*)C + ((size_t)(bidx << 10) + col0 + d) * 2048 + n0 + off;
#pragma unroll
      for (int j = 0; j < 4; ++j)
        *(bf16x8*)(g + j * 8) = *(const bf16x8*)(srcp + j * 8);
    }
  } else {
    const int row_base = by * BM + wy * (BM / 2);
    const int col_base = bx * BN + wx * (BN / 2);
#pragma unroll
    for (int mt = 0; mt < MT; ++mt)
#pragma unroll
      for (int nt = 0; nt < NT; ++nt) {
        const int col = col_base + nt * 16 + l15;
        const float bb = has_bias ? bias[col] : 0.0f;
#pragma unroll
        for (int r = 0; r < 4; ++r) {
          const int row = row_base + mt * 16 + quad * 4 + r;
          float v = acc[mt][nt][r] + bb;
          if constexpr (std::is_same_v<TOUT, bf16>)
            C[(size_t)row * N + col] = __float2bfloat16(v);
          else
            C[(size_t)row * N + col] = v;
        }
      }
  }
}

// single-GEMM wrapper with flattened XCD swizzle (nwg % 8 == 0)
template <int BM, int BN, int TMODE, typename TOUT>
__global__ __launch_bounds__(256) void gemm_bt_kernel(
    const bf16* __restrict__ A, const bf16* __restrict__ Bt,
    const float* __restrict__ bias, TOUT* __restrict__ C,
    int N, int K, int has_bias)
{
  __shared__ __align__(16) bf16 smem[2 * (BM + BN) * 64];
  const int nwg = gridDim.x * gridDim.y;
  const int orig = blockIdx.y * gridDim.x + blockIdx.x;
  const int s = xcd_swz(orig, nwg);
  gemm_core<BM, BN, TMODE, TOUT>(A, Bt, bias, C, N, K, has_bias,
                                 s % gridDim.x, s / gridDim.x, smem);
}

// ---------------- Flash attention (R17-exact): 2-subtile pipeline + in-register P + MFMA row sums ----------------
// P fully in-register via K-row permutation: LDS slot s (bits n1 n0 q1 q0
// r1 r0) holds global K row g(s) = (n1 q1 q0 n0 r1 r0) within each 64-row
// granule, so the QK^T C/D fragment, exp'd and packed, IS the 16x16x32 PV
// B-operand (col=l15, k=quad*8..+7). 16 iterations stage a 128-row K/V tile
// (two 64-row sub-tiles) per pinned-barrier pair with vmcnt(8). Row sums
// via ones-A MFMA. XCD-affine (b,h) grouping — flat 512-block grid,
// bh = (bid&7) + 8*(bid>>7), qt = (bid>>3)&15: all 16 q-tiles of one (b,h)
// on the same XCD under round-robin dispatch -> 512KB K/V panel stays
// L2-resident (verified: FETCH 73.8 -> 12.3MB). Best measured: 47.8us.
__global__ __launch_bounds__(256) void flash_kernel(
    const bf16* __restrict__ Q, const bf16* __restrict__ Km,
    const bf16* __restrict__ Vt, bf16* __restrict__ O)
{
  __shared__ __align__(16) bf16 smem[8192 + 16384 + 16384];  // 80KB; 2 blocks/CU (grid-limited anyway)
  bf16* lQ = smem;                  // 128x64
  bf16* lKb = smem + 8192;          // 2 x (2 x 64x64)
  bf16* lVb = smem + 8192 + 16384;  // 2 x (2 x 64x64)
  const int t = threadIdx.x;
  const int w = t >> 6, lane = t & 63, l15 = lane & 15, quad = lane >> 4;
  const int bid = blockIdx.x;
  const int qt = (bid >> 3) & 15;               // q-tile within (b,h)
  const int bh = (bid & 7) + ((bid >> 7) << 3); // XCD-affine (b,h) group
  const int b = bh >> 4, h = bh & 15;
  const int qrow0 = b * 2048 + qt * 128;
  const bf16* qbase = Q + (size_t)qrow0 * 1024 + h * 64;
  const bf16* kbase = Km + ((size_t)(b * 2048)) * 1024 + h * 64;
  const bf16* vbase = Vt + ((size_t)(b * 1024 + h * 64)) * 2048;

  const int sr0 = t >> 3, sc0 = ((t & 7) ^ (sr0 & 7)) << 3;
  const int sr1 = (256 + t) >> 3, sc1 = (((256 + t) & 7) ^ (sr1 & 7)) << 3;
  // K-row permutation g(s): (n1 n0 q1 q0 r1 r0) -> (n1 q1 q0 n0 r1 r0)
  const int gr0 = (sr0 & 0x23) | ((sr0 & 0x0C) << 1) | ((sr0 & 0x10) >> 2);
  const int gr1 = (sr1 & 0x23) | ((sr1 & 0x0C) << 1) | ((sr1 & 0x10) >> 2);
  const bf16* kp0 = kbase + gr0 * 1024 + sc0;
  const bf16* kp1 = kbase + gr1 * 1024 + sc1;
  const bf16* vp0 = vbase + sr0 * 2048 + sc0;
  const bf16* vp1 = vbase + sr1 * 2048 + sc1;

  // stage one 64-row K sub-tile (rows kro..+63) and 64-col V sub-tile into dst
  auto stage_kv = [&](bf16* kdst, bf16* vdst, int kro, int vco) {
    const int ko = kro << 10;  // kro * 1024
    gl_lds16(kp0 + ko, kdst + t * 8);
    gl_lds16(kp1 + ko, kdst + (256 + t) * 8);
    gl_lds16(vp0 + vco, vdst + t * 8);
    gl_lds16(vp1 + vco, vdst + (256 + t) * 8);
  };

  // prologue: stage Q (4) + K/V tile 0 (8: two sub-tiles)
#pragma unroll
  for (int i = 0; i < 4; ++i) {
    int s = i * 256 + t;
    int row = s >> 3, c = (s & 7) ^ (row & 7);
    gl_lds16(qbase + (size_t)row * 1024 + (c << 3), lQ + s * 8);
  }
  stage_kv(lKb, lVb, 0, 0);
  stage_kv(lKb + 4096, lVb + 4096, 64, 64);
  asm volatile("s_waitcnt vmcnt(8)" ::: "memory");  // Q done (in-order); tile0 in flight
  barrier_pinned();

  const int sw = (quad ^ (l15 & 7)) << 3;
  bf16x8 qf[2][2];
#pragma unroll
  for (int mset = 0; mset < 2; ++mset) {
    const int row = w * 32 + mset * 16 + l15;
    qf[mset][0] = *(const bf16x8*)&lQ[row * 64 + sw];
    qf[mset][1] = *(const bf16x8*)&lQ[row * 64 + (sw ^ 32)];
  }

  f32x4 o_acc[4][2] = {};   // [dt][mset]: O^T row d = dt*16+quad*4+r, col m = mset*16+l15
  f32x4 s_acc[2] = {};      // ones-MFMA row sums (all rows identical per lane col)
  const short ONEB = (short)0x3F80;  // bf16 1.0
  const bf16x8 ones = {ONEB, ONEB, ONEB, ONEB, ONEB, ONEB, ONEB, ONEB};

  for (int kt = 0; kt < 16; ++kt) {
    const int cur = kt & 1;
    bf16* lK = lKb + cur * 8192;
    bf16* lV = lVb + cur * 8192;
    bf16* lKn = lKb + (cur ^ 1) * 8192;
    bf16* lVn = lVb + (cur ^ 1) * 8192;

    barrier_pinned();  // all waves done reading buf cur^1
    {
      const int ktn = (kt + 1) & 15;  // wrap: restage tile 0 into dead buf
      const int kro = ktn << 7;       // ktn*128 K-rows
      const int vco = ktn << 7;       // ktn*128 V-cols
      stage_kv(lKn, lVn, kro, vco);
      stage_kv(lKn + 4096, lVn + 4096, kro + 64, vco + 64);
    }
    asm volatile("s_waitcnt vmcnt(8)" ::: "memory");  // current tile landed; next in flight
    barrier_pinned();  // tile kt visible to all waves; sub-tile reads pinned below

#pragma unroll
    for (int sub = 0; sub < 2; ++sub) {
      bf16* lKs = lK + sub * 4096;
      bf16* lVs = lV + sub * 4096;

      bf16x8 kf[4][2];
#pragma unroll
      for (int nt = 0; nt < 4; ++nt) {
        kf[nt][0] = *(const bf16x8*)&lKs[(nt * 16 + l15) * 64 + sw];
        kf[nt][1] = *(const bf16x8*)&lKs[(nt * 16 + l15) * 64 + (sw ^ 32)];
      }

      // S^T (log2-domain) + v_exp + truncating pack straight into B-operand regs
      bf16x8 pa[2][2];
#pragma unroll
      for (int mset = 0; mset < 2; ++mset) {
#pragma unroll
        for (int half = 0; half < 2; ++half) {
          f32x4 z0 = {}, z1 = {};
          z0 = MFMA_BF16(kf[2 * half + 0][0], qf[mset][0], z0);
          z0 = MFMA_BF16(kf[2 * half + 0][1], qf[mset][1], z0);
          z1 = MFMA_BF16(kf[2 * half + 1][0], qf[mset][0], z1);
          z1 = MFMA_BF16(kf[2 * half + 1][1], qf[mset][1], z1);
          f32x4 p0, p1;
#pragma unroll
          for (int r = 0; r < 4; ++r) {
            p0[r] = __builtin_amdgcn_exp2f(z0[r]);
            p1[r] = __builtin_amdgcn_exp2f(z1[r]);
          }
          union { unsigned u[4]; bf16x8 v; } cv;
          cv.u[0] = pack_bf16x2_trunc(p0[0], p0[1]);
          cv.u[1] = pack_bf16x2_trunc(p0[2], p0[3]);
          cv.u[2] = pack_bf16x2_trunc(p1[0], p1[1]);
          cv.u[3] = pack_bf16x2_trunc(p1[2], p1[3]);
          pa[mset][half] = cv.v;
        }
      }

      bf16x8 vf[4][2];
#pragma unroll
      for (int dt = 0; dt < 4; ++dt) {
        vf[dt][0] = *(const bf16x8*)&lVs[(dt * 16 + l15) * 64 + sw];
        vf[dt][1] = *(const bf16x8*)&lVs[(dt * 16 + l15) * 64 + (sw ^ 32)];
      }

      __builtin_amdgcn_s_setprio(1);
#pragma unroll
      for (int mset = 0; mset < 2; ++mset) {
        s_acc[mset] = MFMA_BF16(ones, pa[mset][0], s_acc[mset]);
        s_acc[mset] = MFMA_BF16(ones, pa[mset][1], s_acc[mset]);
#pragma unroll
        for (int dt = 0; dt < 4; ++dt) {
          o_acc[dt][mset] = MFMA_BF16(vf[dt][0], pa[mset][0], o_acc[dt][mset]);
          o_acc[dt][mset] = MFMA_BF16(vf[dt][1], pa[mset][1], o_acc[dt][mset]);
        }
      }
      __builtin_amdgcn_s_setprio(0);
    }
  }

  // epilogue: divide + store O^T fragments (row sum already complete per lane)
#pragma unroll
  for (int mset = 0; mset < 2; ++mset) {
    const float inv = 1.0f / s_acc[mset][0];
    const int m = qrow0 + w * 32 + mset * 16 + l15;
#pragma unroll
    for (int dt = 0; dt < 4; ++dt) {
      uint2 ok;
      ok.x = pack_bf16x2(o_acc[dt][mset][0] * inv, o_acc[dt][mset][1] * inv);
      ok.y = pack_bf16x2(o_acc[dt][mset][2] * inv, o_acc[dt][mset][3] * inv);
      *(uint2*)&O[(size_t)m * 1024 + h * 64 + dt * 16 + quad * 4] = ok;
    }
  }
}

extern "C" void kernel_launch(void* const* d_in, const int* in_sizes, int n_in,
                              void* d_out, int out_size, void* d_ws, size_t ws_size,
                              hipStream_t stream)
{
  (void)in_sizes; (void)n_in; (void)out_size; (void)ws_size;
  const float* keys   = (const float*)d_in[0];
  const float* values = (const float*)d_in[1];
  const float* qk_g   = (const float*)d_in[2];
  const float* qk_b   = (const float*)d_in[3];
  const float* val_g  = (const float*)d_in[4];
  const float* val_b  = (const float*)d_in[5];
  const float* key_g  = (const float*)d_in[6];
  const float* key_b  = (const float*)d_in[7];
  const float* qry_g  = (const float*)d_in[8];
  const float* qry_b  = (const float*)d_in[9];
  const float* w_qk   = (const float*)d_in[10];
  const float* w_v    = (const float*)d_in[11];
  const float* w_out  = (const float*)d_in[12];
  const float* b_out  = (const float*)d_in[13];
  float* out = (float*)d_out;

  const float CEXP = 0.03125f * 1.44269504f;  // ID^-0.5 * log2(e), folded into q-LN

  // R14 workspace map (48MB) — lifetime-disjoint.
  // P1: prep (writes keys_ln, values_ln, weights)
  // P2a: qk GEMM (reads keys_ln/wqkT; writes qk)
  // P2b: vt GEMM (reads values_ln/wvT; writes vt — disjoint from qk)
  // P3: q/k LN (reads qk; writes qln over keys_ln, kln over values_ln — both dead)
  // P4: flash (reads qln/kln/vt; writes attn over qk[0:8MB] — qk dead)
  // P5: out GEMM (reads attn/woutT; writes d_out)
  char* ws = (char*)d_ws;
  const size_t MB = 1024 * 1024;
  bf16* keys_ln   = (bf16*)(ws + 0);        // 8MB   P1w, P2a r
  bf16* values_ln = (bf16*)(ws + 8 * MB);   // 8MB   P1w, P2b r
  bf16* qk        = (bf16*)(ws + 16 * MB);  // 16MB  P2a w, P3r
  bf16* vt        = (bf16*)(ws + 32 * MB);  // 8MB   P2b w, P4r
  bf16* qln       = (bf16*)(ws + 0);        // 8MB   P3w, P4r (reuses keys_ln)
  bf16* kln       = (bf16*)(ws + 8 * MB);   // 8MB   P3w, P4r (reuses values_ln)
  bf16* attn      = (bf16*)(ws + 16 * MB);  // 8MB   P4w, P5r (reuses qk)
  bf16* wqkT      = (bf16*)(ws + 40 * MB);  // 4MB   P1w, P2a r
  bf16* wvT       = (bf16*)(ws + 44 * MB);  // 2MB   P1w, P2b r
  bf16* woutT     = (bf16*)(ws + 46 * MB);  // 2MB   P1w, P5r

  // P1: input layernorms + all weight transposes (independent work, one launch)
  prep_kernel<<<dim3(9216), 256, 0, stream>>>(
      keys, values, qk_g, qk_b, val_g, val_b, keys_ln, values_ln,
      w_qk, wqkT, w_v, wvT, w_out, woutT);
  // P2a: qk = keys_ln @ w_qk (4096x2048), 128x64 tile, 1024 blocks
  gemm_bt_kernel<128, 64, 0, bf16><<<dim3(32, 32), 256, 0, stream>>>(
      keys_ln, wqkT, nullptr, qk, 2048, 1024, 0);
  // P2b: vt = (values_ln @ w_v)^T (4096x1024 -> transposed store), 128x64 tile, 512 blocks
  gemm_bt_kernel<128, 64, 1, bf16><<<dim3(16, 32), 256, 0, stream>>>(
      values_ln, wvT, nullptr, vt, 1024, 1024, 0);
  // P3: q/k layernorms; qln pre-scaled by CEXP
  ln2_kernel<bf16><<<dim3(4096, 2), 256, 0, stream>>>(
      qk, qk + 1024, 2048, qry_g, qry_b, key_g, key_b, qln, kln, 1024, CEXP, 1.0f);
  // P4: flash attention -> attn (flat 512-block grid, XCD-affine bh grouping)
  flash_kernel<<<dim3(512), 256, 0, stream>>>(qln, kln, vt, attn);
  // P5: out = attn @ w_out + b_out (fp32 out), 128x64 tile, 512 blocks, 3 blocks/CU
  gemm_bt_kernel<128, 64, 0, float><<<dim3(16, 32), 256, 0, stream>>>(
      attn, woutT, b_out, out, 1024, 1024, 1);
}

// Round 12
// 213.821 us; speedup vs baseline: 1.0456x; 1.0456x over previous
//
#include <hip/hip_runtime.h>
#include <hip/hip_bf16.h>
#include <type_traits>

// SelfAttention fused block, MI355X/gfx950.
// R21: consolidation to global-best verified config. R20's diagnostic
//      split proved NO single non-flash dispatch exceeds ~47us (the
//      "P2 elephant" is falsified — time is spread across medium
//      dispatches at their structural rates for K=1024 shapes).
//      Config: P2 = dual GEMM (merged, 1536 blocks — saves a boundary,
//      vt fills qk's tail), P5 = 128x64 @3/CU (R16 best), flash =
//      R17-exact (best measured 47.8us). R14 lifetime-disjoint
//      workspace map. 5 launches.

typedef __hip_bfloat16 bf16;
typedef __attribute__((ext_vector_type(8))) short bf16x8;
typedef __attribute__((ext_vector_type(4))) float f32x4;

#define MFMA_BF16(a, b, c) __builtin_amdgcn_mfma_f32_16x16x32_bf16((a), (b), (c), 0, 0, 0)

__device__ __forceinline__ float us2f(unsigned short u) {
  unsigned int v = ((unsigned int)u) << 16;
  return __builtin_bit_cast(float, v);
}

__device__ __forceinline__ unsigned pack_bf16x2(float a, float b) {  // RNE (epilogues)
  union { __hip_bfloat162 h; unsigned u; } cv;
  cv.h = __float22bfloat162_rn(float2{a, b});
  return cv.u;
}

__device__ __forceinline__ unsigned pack_bf16x2_trunc(float a, float b) {  // 1x v_perm
  return __builtin_amdgcn_perm(__builtin_bit_cast(unsigned, b),
                               __builtin_bit_cast(unsigned, a), 0x07060302u);
}

// async global->LDS, 16B per lane; lane i's dest = wave-uniform base + i*16
__device__ __forceinline__ void gl_lds16(const bf16* g, bf16* l) {
  __builtin_amdgcn_global_load_lds(
      (const __attribute__((address_space(1))) void*)g,
      (__attribute__((address_space(3))) void*)l, 16, 0, 0);
}

// raw barrier + compile-time scheduling fence: nothing (esp. plain LDS
// loads) may move across this sync point in either direction.
__device__ __forceinline__ void barrier_pinned() {
  __builtin_amdgcn_s_barrier();
  __builtin_amdgcn_sched_barrier(0);
}

// m204 bijective XCD swizzle; requires nwg % 8 == 0.
__device__ __forceinline__ int xcd_swz(int orig, int nwg) {
  return (orig & 7) * (nwg >> 3) + (orig >> 3);
}

// ---------------- LayerNorm row core (one 256-thread block per row) ----------------
template <typename TIN>
__device__ __forceinline__ void ln_core(
    const TIN* __restrict__ in, const float* __restrict__ gamma,
    const float* __restrict__ beta, bf16* __restrict__ out,
    int stride, int D, float sc, int row, float* red)
{
  const int t = threadIdx.x;
  float x0, x1, x2, x3;
  if constexpr (std::is_same_v<TIN, float>) {
    float4 u = *(const float4*)(in + (size_t)row * stride + t * 4);
    x0 = u.x; x1 = u.y; x2 = u.z; x3 = u.w;
  } else {
    ushort4 u = *(const ushort4*)(in + (size_t)row * stride + t * 4);
    x0 = us2f(u.x); x1 = us2f(u.y); x2 = us2f(u.z); x3 = us2f(u.w);
  }
  float s = x0 + x1 + x2 + x3;
  float s2 = x0 * x0 + x1 * x1 + x2 * x2 + x3 * x3;
#pragma unroll
  for (int m = 1; m < 64; m <<= 1) {
    s += __shfl_xor(s, m);
    s2 += __shfl_xor(s2, m);
  }
  const int w = t >> 6, lane = t & 63;
  if (lane == 0) { red[w] = s; red[4 + w] = s2; }
  __syncthreads();
  if (t == 0) {
    float S = red[0] + red[1] + red[2] + red[3];
    float S2 = red[4] + red[5] + red[6] + red[7];
    float mu = S / (float)D;
    float var = S2 / (float)D - mu * mu;
    red[8] = mu;
    red[9] = rsqrtf(var + 1e-5f);
  }
  __syncthreads();
  const float mu = red[8], rs = red[9];
  float4 g4 = *(const float4*)(gamma + t * 4);
  float4 b4 = *(const float4*)(beta + t * 4);
  uint2 o;
  o.x = pack_bf16x2(((x0 - mu) * rs * g4.x + b4.x) * sc, ((x1 - mu) * rs * g4.y + b4.y) * sc);
  o.y = pack_bf16x2(((x2 - mu) * rs * g4.z + b4.z) * sc, ((x3 - mu) * rs * g4.w + b4.w) * sc);
  *(uint2*)(out + (size_t)row * D + t * 4) = o;
}

// ---------------- standalone LN pair (P3) ----------------
template <typename TIN>
__global__ __launch_bounds__(256) void ln2_kernel(
    const TIN* __restrict__ in0, const TIN* __restrict__ in1, int stride,
    const float* __restrict__ g0, const float* __restrict__ b0,
    const float* __restrict__ g1, const float* __restrict__ b1,
    bf16* __restrict__ out0, bf16* __restrict__ out1, int D,
    float sc0, float sc1)
{
  __shared__ float red[10];
  const int which = blockIdx.y;
  ln_core<TIN>(which ? in1 : in0, which ? g1 : g0, which ? b1 : b0,
               which ? out1 : out0, stride, D, which ? sc1 : sc0,
               blockIdx.x, red);
}

// ---------------- 64x64 f32->bf16 transpose tile core ----------------
__device__ __forceinline__ void transpose_core(
    const float* __restrict__ in, bf16* __restrict__ out, int C,
    int r0, int c0, float (*tile)[68])
{
  const int R = 1024;
  const int t = threadIdx.x;
  const int lr = t >> 2, lc = (t & 3) * 16;
  const float* src = in + (size_t)(r0 + lr) * C + (c0 + lc);
#pragma unroll
  for (int i = 0; i < 4; ++i) {
    float4 u = *(const float4*)(src + i * 4);
    tile[lr][lc + i * 4 + 0] = u.x;
    tile[lr][lc + i * 4 + 1] = u.y;
    tile[lr][lc + i * 4 + 2] = u.z;
    tile[lr][lc + i * 4 + 3] = u.w;
  }
  __syncthreads();
  __align__(16) bf16 tmp[16];
#pragma unroll
  for (int j = 0; j < 16; ++j) tmp[j] = __float2bfloat16(tile[lc + j][lr]);
  bf16* dst = out + (size_t)(c0 + lr) * R + (r0 + lc);
  *(bf16x8*)dst       = *(const bf16x8*)&tmp[0];
  *(bf16x8*)(dst + 8) = *(const bf16x8*)&tmp[8];
}

// ---------------- prep: input LNs (8192 blocks) + 3 weight transposes (1024 blocks) ----------------
__global__ __launch_bounds__(256) void prep_kernel(
    const float* __restrict__ keys, const float* __restrict__ values,
    const float* __restrict__ qk_g, const float* __restrict__ qk_b,
    const float* __restrict__ val_g, const float* __restrict__ val_b,
    bf16* __restrict__ keys_ln, bf16* __restrict__ values_ln,
    const float* __restrict__ w_qk, bf16* __restrict__ wqkT,
    const float* __restrict__ w_v, bf16* __restrict__ wvT,
    const float* __restrict__ w_out, bf16* __restrict__ woutT)
{
  __shared__ float tile[64][68];
  __shared__ float red[10];
  const int bid = blockIdx.x;
  if (bid < 8192) {
    const int row = bid >> 1, which = bid & 1;
    ln_core<float>(which ? values : keys, which ? val_g : qk_g,
                   which ? val_b : qk_b, which ? values_ln : keys_ln,
                   1024, 1024, 1.0f, row, red);
  } else {
    const int tz = bid - 8192;
    if (tz < 512) {
      transpose_core(w_qk, wqkT, 2048, (tz >> 5) * 64, (tz & 31) * 64, tile);
    } else if (tz < 768) {
      const int s = tz - 512;
      transpose_core(w_v, wvT, 1024, (s >> 4) * 64, (s & 15) * 64, tile);
    } else {
      const int s = tz - 768;
      transpose_core(w_out, woutT, 1024, (s >> 4) * 64, (s & 15) * 64, tile);
    }
  }
}

// ---------------- GEMM core: C(M,N) = A(M,K) @ Bt(N,K)^T (+bias), bf16 in, fp32 accum ----------------
// BK=64, double-buffered K-loop with counted vmcnt (ASL+BSL loads stay in
// flight across the compute phase). XOR chunk swizzle (c ^ (row&7)) on
// 128B LDS rows -> conflict-free ds_read_b128 frags. 2x2 waves. All raw
// barriers are sched_barrier(0)-pinned so frag ds_reads cannot hoist into
// the staging/vmcnt window. TMODE 1: coalesced vt store via LDS bounce:
// vt[((row>>11)*1024 + col)*2048 + (row&2047)].
template <int BM, int BN, int TMODE, typename TOUT>
__device__ __forceinline__ void gemm_core(
    const bf16* __restrict__ A, const bf16* __restrict__ Bt,
    const float* __restrict__ bias, TOUT* __restrict__ C,
    int N, int K, int has_bias, int bx, int by, bf16* smem)
{
  constexpr int MT = BM / 32, NT = BN / 32;     // 16x16 frags per wave
  constexpr int ASL = BM / 32, BSL = BN / 32;   // 16B staging slots per thread (BK=64)
  constexpr int BUFE = (BM + BN) * 64;          // elements per buffer
  const int t = threadIdx.x;
  const int w = t >> 6, lane = t & 63, l15 = lane & 15, quad = lane >> 4;
  const int wy = w >> 1, wx = w & 1;
  const bf16* Ab = A + (size_t)by * BM * K;
  const bf16* Bb = Bt + (size_t)bx * BN * K;
  f32x4 acc[MT][NT] = {};

  // per-thread staging sources, hoisted out of the K-loop (addr-mul once)
  const bf16* aptr[ASL];
  const bf16* bptr[BSL];
#pragma unroll
  for (int i = 0; i < ASL; ++i) {
    int s = i * 256 + t, row = s >> 3, c = (s & 7) ^ (row & 7);
    aptr[i] = Ab + (size_t)row * K + (c << 3);
  }
#pragma unroll
  for (int i = 0; i < BSL; ++i) {
    int s = i * 256 + t, row = s >> 3, c = (s & 7) ^ (row & 7);
    bptr[i] = Bb + (size_t)row * K + (c << 3);
  }

  auto stage = [&](bf16* buf, int kc) {
#pragma unroll
    for (int i = 0; i < ASL; ++i)
      gl_lds16(aptr[i] + kc, buf + (i * 256 + t) * 8);
#pragma unroll
    for (int i = 0; i < BSL; ++i)
      gl_lds16(bptr[i] + kc, buf + BM * 64 + (i * 256 + t) * 8);
  };

  const int sw = (quad ^ (l15 & 7)) << 3;
  const int NK = K >> 6;

  stage(smem, 0);  // prologue: tile 0 into buf 0

  for (int kt = 0; kt < NK; ++kt) {
    const int cur = kt & 1;
    bf16* lA = smem + cur * BUFE;
    bf16* lB = lA + BM * 64;
    barrier_pinned();  // all waves done reading buf cur^1
    if (kt + 1 < NK) {
      stage(smem + (cur ^ 1) * BUFE, (kt + 1) << 6);
      if constexpr (ASL + BSL == 8)
        asm volatile("s_waitcnt vmcnt(8)" ::: "memory");  // tile kt landed; kt+1 in flight
      else if constexpr (ASL + BSL == 6)
        asm volatile("s_waitcnt vmcnt(6)" ::: "memory");
      else
        asm volatile("s_waitcnt vmcnt(4)" ::: "memory");
    } else {
      asm volatile("s_waitcnt vmcnt(0)" ::: "memory");
    }
    barrier_pinned();  // staged data visible to all waves; reads pinned below

#pragma unroll
    for (int h = 0; h < 2; ++h) {
      const int so = sw ^ (h << 5);
      bf16x8 af[MT], bfr[NT];
#pragma unroll
      for (int mt = 0; mt < MT; ++mt)
        af[mt] = *(const bf16x8*)&lA[(wy * (BM / 2) + mt * 16 + l15) * 64 + so];
#pragma unroll
      for (int nt = 0; nt < NT; ++nt)
        bfr[nt] = *(const bf16x8*)&lB[(wx * (BN / 2) + nt * 16 + l15) * 64 + so];
#pragma unroll
      for (int mt = 0; mt < MT; ++mt)
#pragma unroll
        for (int nt = 0; nt < NT; ++nt)
          acc[mt][nt] = MFMA_BF16(af[mt], bfr[nt], acc[mt][nt]);
    }
  }

  if constexpr (TMODE == 1) {
    // acc: row n = wy*(BM/2)+mt*16+quad*4+r, col d = wx*(BN/2)+nt*16+l15 -> lOut[d][n]
    constexpr int STR = BM + 8;   // keeps d*STR*2 bytes 16B-aligned
    static_assert(BN * STR <= 2 * BUFE, "lOut must fit staging buffers");
    bf16* lOut = smem;            // aliases dead staging buffers
    __syncthreads();
#pragma unroll
    for (int mt = 0; mt < MT; ++mt)
#pragma unroll
      for (int nt = 0; nt < NT; ++nt) {
        const int d = wx * (BN / 2) + nt * 16 + l15;
        const int n = wy * (BM / 2) + mt * 16 + quad * 4;
        uint2 pk;
        pk.x = pack_bf16x2(acc[mt][nt][0], acc[mt][nt][1]);
        pk.y = pack_bf16x2(acc[mt][nt][2], acc[mt][nt][3]);
        *(uint2*)&lOut[d * STR + n] = pk;
      }
    __syncthreads();
    const int row0 = by * BM;
    const int bidx = row0 >> 11, n0 = row0 & 2047;
    const int col0 = bx * BN;
    constexpr int CPR = BM / 32;                  // 32-el chunks per d-row
    constexpr int NITER = (BN * CPR) / 256;
#pragma unroll
    for (int it = 0; it < NITER; ++it) {
      const int idx = it * 256 + t;
      const int d = idx / CPR, off = (idx % CPR) * 32;
      const bf16* srcp = &lOut[d * STR + off];
      bf16* g = (bf16*)C + ((size_t)(bidx << 10) + col0 + d) * 2048 + n0 + off;
#pragma unroll
      for (int j = 0; j < 4; ++j)
        *(bf16x8*)(g + j * 8) = *(const bf16x8*)(srcp + j * 8);
    }
  } else {
    const int row_base = by * BM + wy * (BM / 2);
    const int col_base = bx * BN + wx * (BN / 2);
#pragma unroll
    for (int mt = 0; mt < MT; ++mt)
#pragma unroll
      for (int nt = 0; nt < NT; ++nt) {
        const int col = col_base + nt * 16 + l15;
        const float bb = has_bias ? bias[col] : 0.0f;
#pragma unroll
        for (int r = 0; r < 4; ++r) {
          const int row = row_base + mt * 16 + quad * 4 + r;
          float v = acc[mt][nt][r] + bb;
          if constexpr (std::is_same_v<TOUT, bf16>)
            C[(size_t)row * N + col] = __float2bfloat16(v);
          else
            C[(size_t)row * N + col] = v;
        }
      }
  }
}

// single-GEMM wrapper (P5) with flattened XCD swizzle (nwg % 8 == 0)
template <int BM, int BN, int TMODE, typename TOUT>
__global__ __launch_bounds__(256) void gemm_bt_kernel(
    const bf16* __restrict__ A, const bf16* __restrict__ Bt,
    const float* __restrict__ bias, TOUT* __restrict__ C,
    int N, int K, int has_bias)
{
  __shared__ __align__(16) bf16 smem[2 * (BM + BN) * 64];
  const int nwg = gridDim.x * gridDim.y;
  const int orig = blockIdx.y * gridDim.x + blockIdx.x;
  const int s = xcd_swz(orig, nwg);
  gemm_core<BM, BN, TMODE, TOUT>(A, Bt, bias, C, N, K, has_bias,
                                 s % gridDim.x, s / gridDim.x, smem);
}

// dual GEMM (P2): qk = keys_ln @ wqkT (1024 blocks, 128x64) +
//                 vt = values_ln @ wvT (512 blocks, 128x64, TMODE1)
// NOTE: qk and vt must be DISJOINT workspace regions (concurrent in one
// dispatch) — enforced by the R14 workspace map. XCD swizzle per segment.
__global__ __launch_bounds__(256) void gemm_dual_kernel(
    const bf16* __restrict__ A0, const bf16* __restrict__ B0, bf16* __restrict__ C0,
    const bf16* __restrict__ A1, const bf16* __restrict__ B1, bf16* __restrict__ C1)
{
  __shared__ __align__(16) bf16 smem[2 * 192 * 64];  // 48KB -> 3 blocks/CU
  const int bid = blockIdx.x;
  if (bid < 1024) {
    const int s = xcd_swz(bid, 1024);
    gemm_core<128, 64, 0, bf16>(A0, B0, nullptr, C0, 2048, 1024, 0,
                                s & 31, s >> 5, smem);
  } else {
    const int s = xcd_swz(bid - 1024, 512);
    gemm_core<128, 64, 1, bf16>(A1, B1, nullptr, C1, 1024, 1024, 0,
                                s & 15, s >> 4, smem);
  }
}

// ---------------- Flash attention (R17-exact): 2-subtile pipeline + in-register P + MFMA row sums ----------------
// P fully in-register via K-row permutation: LDS slot s (bits n1 n0 q1 q0
// r1 r0) holds global K row g(s) = (n1 q1 q0 n0 r1 r0) within each 64-row
// granule, so the QK^T C/D fragment, exp'd and packed, IS the 16x16x32 PV
// B-operand (col=l15, k=quad*8..+7). 16 iterations stage a 128-row K/V tile
// (two 64-row sub-tiles) per pinned-barrier pair with vmcnt(8). Row sums
// via ones-A MFMA. XCD-affine (b,h) grouping — flat 512-block grid,
// bh = (bid&7) + 8*(bid>>7), qt = (bid>>3)&15: all 16 q-tiles of one (b,h)
// on the same XCD under round-robin dispatch -> 512KB K/V panel stays
// L2-resident (verified: FETCH 73.8 -> 12.3MB). Best measured: 47.8us.
__global__ __launch_bounds__(256) void flash_kernel(
    const bf16* __restrict__ Q, const bf16* __restrict__ Km,
    const bf16* __restrict__ Vt, bf16* __restrict__ O)
{
  __shared__ __align__(16) bf16 smem[8192 + 16384 + 16384];  // 80KB; 2 blocks/CU (grid-limited anyway)
  bf16* lQ = smem;                  // 128x64
  bf16* lKb = smem + 8192;          // 2 x (2 x 64x64)
  bf16* lVb = smem + 8192 + 16384;  // 2 x (2 x 64x64)
  const int t = threadIdx.x;
  const int w = t >> 6, lane = t & 63, l15 = lane & 15, quad = lane >> 4;
  const int bid = blockIdx.x;
  const int qt = (bid >> 3) & 15;               // q-tile within (b,h)
  const int bh = (bid & 7) + ((bid >> 7) << 3); // XCD-affine (b,h) group
  const int b = bh >> 4, h = bh & 15;
  const int qrow0 = b * 2048 + qt * 128;
  const bf16* qbase = Q + (size_t)qrow0 * 1024 + h * 64;
  const bf16* kbase = Km + ((size_t)(b * 2048)) * 1024 + h * 64;
  const bf16* vbase = Vt + ((size_t)(b * 1024 + h * 64)) * 2048;

  const int sr0 = t >> 3, sc0 = ((t & 7) ^ (sr0 & 7)) << 3;
  const int sr1 = (256 + t) >> 3, sc1 = (((256 + t) & 7) ^ (sr1 & 7)) << 3;
  // K-row permutation g(s): (n1 n0 q1 q0 r1 r0) -> (n1 q1 q0 n0 r1 r0)
  const int gr0 = (sr0 & 0x23) | ((sr0 & 0x0C) << 1) | ((sr0 & 0x10) >> 2);
  const int gr1 = (sr1 & 0x23) | ((sr1 & 0x0C) << 1) | ((sr1 & 0x10) >> 2);
  const bf16* kp0 = kbase + gr0 * 1024 + sc0;
  const bf16* kp1 = kbase + gr1 * 1024 + sc1;
  const bf16* vp0 = vbase + sr0 * 2048 + sc0;
  const bf16* vp1 = vbase + sr1 * 2048 + sc1;

  // stage one 64-row K sub-tile (rows kro..+63) and 64-col V sub-tile into dst
  auto stage_kv = [&](bf16* kdst, bf16* vdst, int kro, int vco) {
    const int ko = kro << 10;  // kro * 1024
    gl_lds16(kp0 + ko, kdst + t * 8);
    gl_lds16(kp1 + ko, kdst + (256 + t) * 8);
    gl_lds16(vp0 + vco, vdst + t * 8);
    gl_lds16(vp1 + vco, vdst + (256 + t) * 8);
  };

  // prologue: stage Q (4) + K/V tile 0 (8: two sub-tiles)
#pragma unroll
  for (int i = 0; i < 4; ++i) {
    int s = i * 256 + t;
    int row = s >> 3, c = (s & 7) ^ (row & 7);
    gl_lds16(qbase + (size_t)row * 1024 + (c << 3), lQ + s * 8);
  }
  stage_kv(lKb, lVb, 0, 0);
  stage_kv(lKb + 4096, lVb + 4096, 64, 64);
  asm volatile("s_waitcnt vmcnt(8)" ::: "memory");  // Q done (in-order); tile0 in flight
  barrier_pinned();

  const int sw = (quad ^ (l15 & 7)) << 3;
  bf16x8 qf[2][2];
#pragma unroll
  for (int mset = 0; mset < 2; ++mset) {
    const int row = w * 32 + mset * 16 + l15;
    qf[mset][0] = *(const bf16x8*)&lQ[row * 64 + sw];
    qf[mset][1] = *(const bf16x8*)&lQ[row * 64 + (sw ^ 32)];
  }

  f32x4 o_acc[4][2] = {};   // [dt][mset]: O^T row d = dt*16+quad*4+r, col m = mset*16+l15
  f32x4 s_acc[2] = {};      // ones-MFMA row sums (all rows identical per lane col)
  const short ONEB = (short)0x3F80;  // bf16 1.0
  const bf16x8 ones = {ONEB, ONEB, ONEB, ONEB, ONEB, ONEB, ONEB, ONEB};

  for (int kt = 0; kt < 16; ++kt) {
    const int cur = kt & 1;
    bf16* lK = lKb + cur * 8192;
    bf16* lV = lVb + cur * 8192;
    bf16* lKn = lKb + (cur ^ 1) * 8192;
    bf16* lVn = lVb + (cur ^ 1) * 8192;

    barrier_pinned();  // all waves done reading buf cur^1
    {
      const int ktn = (kt + 1) & 15;  // wrap: restage tile 0 into dead buf
      const int kro = ktn << 7;       // ktn*128 K-rows
      const int vco = ktn << 7;       // ktn*128 V-cols
      stage_kv(lKn, lVn, kro, vco);
      stage_kv(lKn + 4096, lVn + 4096, kro + 64, vco + 64);
    }
    asm volatile("s_waitcnt vmcnt(8)" ::: "memory");  // current tile landed; next in flight
    barrier_pinned();  // tile kt visible to all waves; sub-tile reads pinned below

#pragma unroll
    for (int sub = 0; sub < 2; ++sub) {
      bf16* lKs = lK + sub * 4096;
      bf16* lVs = lV + sub * 4096;

      bf16x8 kf[4][2];
#pragma unroll
      for (int nt = 0; nt < 4; ++nt) {
        kf[nt][0] = *(const bf16x8*)&lKs[(nt * 16 + l15) * 64 + sw];
        kf[nt][1] = *(const bf16x8*)&lKs[(nt * 16 + l15) * 64 + (sw ^ 32)];
      }

      // S^T (log2-domain) + v_exp + truncating pack straight into B-operand regs
      bf16x8 pa[2][2];
#pragma unroll
      for (int mset = 0; mset < 2; ++mset) {
#pragma unroll
        for (int half = 0; half < 2; ++half) {
          f32x4 z0 = {}, z1 = {};
          z0 = MFMA_BF16(kf[2 * half + 0][0], qf[mset][0], z0);
          z0 = MFMA_BF16(kf[2 * half + 0][1], qf[mset][1], z0);
          z1 = MFMA_BF16(kf[2 * half + 1][0], qf[mset][0], z1);
          z1 = MFMA_BF16(kf[2 * half + 1][1], qf[mset][1], z1);
          f32x4 p0, p1;
#pragma unroll
          for (int r = 0; r < 4; ++r) {
            p0[r] = __builtin_amdgcn_exp2f(z0[r]);
            p1[r] = __builtin_amdgcn_exp2f(z1[r]);
          }
          union { unsigned u[4]; bf16x8 v; } cv;
          cv.u[0] = pack_bf16x2_trunc(p0[0], p0[1]);
          cv.u[1] = pack_bf16x2_trunc(p0[2], p0[3]);
          cv.u[2] = pack_bf16x2_trunc(p1[0], p1[1]);
          cv.u[3] = pack_bf16x2_trunc(p1[2], p1[3]);
          pa[mset][half] = cv.v;
        }
      }

      bf16x8 vf[4][2];
#pragma unroll
      for (int dt = 0; dt < 4; ++dt) {
        vf[dt][0] = *(const bf16x8*)&lVs[(dt * 16 + l15) * 64 + sw];
        vf[dt][1] = *(const bf16x8*)&lVs[(dt * 16 + l15) * 64 + (sw ^ 32)];
      }

      __builtin_amdgcn_s_setprio(1);
#pragma unroll
      for (int mset = 0; mset < 2; ++mset) {
        s_acc[mset] = MFMA_BF16(ones, pa[mset][0], s_acc[mset]);
        s_acc[mset] = MFMA_BF16(ones, pa[mset][1], s_acc[mset]);
#pragma unroll
        for (int dt = 0; dt < 4; ++dt) {
          o_acc[dt][mset] = MFMA_BF16(vf[dt][0], pa[mset][0], o_acc[dt][mset]);
          o_acc[dt][mset] = MFMA_BF16(vf[dt][1], pa[mset][1], o_acc[dt][mset]);
        }
      }
      __builtin_amdgcn_s_setprio(0);
    }
  }

  // epilogue: divide + store O^T fragments (row sum already complete per lane)
#pragma unroll
  for (int mset = 0; mset < 2; ++mset) {
    const float inv = 1.0f / s_acc[mset][0];
    const int m = qrow0 + w * 32 + mset * 16 + l15;
#pragma unroll
    for (int dt = 0; dt < 4; ++dt) {
      uint2 ok;
      ok.x = pack_bf16x2(o_acc[dt][mset][0] * inv, o_acc[dt][mset][1] * inv);
      ok.y = pack_bf16x2(o_acc[dt][mset][2] * inv, o_acc[dt][mset][3] * inv);
      *(uint2*)&O[(size_t)m * 1024 + h * 64 + dt * 16 + quad * 4] = ok;
    }
  }
}

extern "C" void kernel_launch(void* const* d_in, const int* in_sizes, int n_in,
                              void* d_out, int out_size, void* d_ws, size_t ws_size,
                              hipStream_t stream)
{
  (void)in_sizes; (void)n_in; (void)out_size; (void)ws_size;
  const float* keys   = (const float*)d_in[0];
  const float* values = (const float*)d_in[1];
  const float* qk_g   = (const float*)d_in[2];
  const float* qk_b   = (const float*)d_in[3];
  const float* val_g  = (const float*)d_in[4];
  const float* val_b  = (const float*)d_in[5];
  const float* key_g  = (const float*)d_in[6];
  const float* key_b  = (const float*)d_in[7];
  const float* qry_g  = (const float*)d_in[8];
  const float* qry_b  = (const float*)d_in[9];
  const float* w_qk   = (const float*)d_in[10];
  const float* w_v    = (const float*)d_in[11];
  const float* w_out  = (const float*)d_in[12];
  const float* b_out  = (const float*)d_in[13];
  float* out = (float*)d_out;

  const float CEXP = 0.03125f * 1.44269504f;  // ID^-0.5 * log2(e), folded into q-LN

  // R14 workspace map (48MB) — lifetime-disjoint under the merged schedule.
  // P1: prep (writes keys_ln, values_ln, weights)
  // P2: dual GEMM (reads keys_ln/values_ln/wqkT/wvT; writes qk, vt — DISJOINT)
  // P3: q/k LN (reads qk; writes qln over keys_ln, kln over values_ln — both dead)
  // P4: flash (reads qln/kln/vt; writes attn over qk[0:8MB] — qk dead)
  // P5: out GEMM (reads attn/woutT; writes d_out)
  char* ws = (char*)d_ws;
  const size_t MB = 1024 * 1024;
  bf16* keys_ln   = (bf16*)(ws + 0);        // 8MB   P1w, P2r
  bf16* values_ln = (bf16*)(ws + 8 * MB);   // 8MB   P1w, P2r
  bf16* qk        = (bf16*)(ws + 16 * MB);  // 16MB  P2w, P3r
  bf16* vt        = (bf16*)(ws + 32 * MB);  // 8MB   P2w, P4r
  bf16* qln       = (bf16*)(ws + 0);        // 8MB   P3w, P4r (reuses keys_ln)
  bf16* kln       = (bf16*)(ws + 8 * MB);   // 8MB   P3w, P4r (reuses values_ln)
  bf16* attn      = (bf16*)(ws + 16 * MB);  // 8MB   P4w, P5r (reuses qk)
  bf16* wqkT      = (bf16*)(ws + 40 * MB);  // 4MB   P1w, P2r
  bf16* wvT       = (bf16*)(ws + 44 * MB);  // 2MB   P1w, P2r
  bf16* woutT     = (bf16*)(ws + 46 * MB);  // 2MB   P1w, P5r

  // P1: input layernorms + all weight transposes (independent work, one launch)
  prep_kernel<<<dim3(9216), 256, 0, stream>>>(
      keys, values, qk_g, qk_b, val_g, val_b, keys_ln, values_ln,
      w_qk, wqkT, w_v, wvT, w_out, woutT);
  // P2: qk = keys_ln @ w_qk (1024 blocks) + vt = values_ln @ w_v transposed (512 blocks)
  gemm_dual_kernel<<<dim3(1536), 256, 0, stream>>>(
      keys_ln, wqkT, qk, values_ln, wvT, vt);
  // P3: q/k layernorms; qln pre-scaled by CEXP
  ln2_kernel<bf16><<<dim3(4096, 2), 256, 0, stream>>>(
      qk, qk + 1024, 2048, qry_g, qry_b, key_g, key_b, qln, kln, 1024, CEXP, 1.0f);
  // P4: flash attention -> attn (flat 512-block grid, XCD-affine bh grouping)
  flash_kernel<<<dim3(512), 256, 0, stream>>>(qln, kln, vt, attn);
  // P5: out = attn @ w_out + b_out (fp32 out), 128x64 tile, 512 blocks, 3 blocks/CU
  gemm_bt_kernel<128, 64, 0, float><<<dim3(16, 32), 256, 0, stream>>>(
      attn, woutT, b_out, out, 1024, 1024, 1);
}

// Round 13
// 210.480 us; speedup vs baseline: 1.0622x; 1.0159x over previous
//
#include <hip/hip_runtime.h>
#include <hip/hip_bf16.h>
#include <type_traits>

// SelfAttention fused block, MI355X/gfx950.
// R22: wave-per-row LayerNorm. Both LN passes (P1 input LNs, P3 q/k LNs)
//      move from 1-row-per-256-thread-block (LDS + 2 syncthreads + t==0
//      serialization per row) to 4-rows-per-block, one 64-lane wave per
//      row, 16 els/lane (lane*4 + j*256 layout, dense per-instr
//      coalescing), pure shfl_xor reduce — no LDS, no barriers, 4x fewer
//      blocks. Same formula (D=1024, E[x^2]-mu^2), eps-level sum-order
//      change only. Everything else byte-identical to R21 (best verified:
//      dual GEMM 1536 blocks, P5 128x64 @3/CU, flash R17-exact 47.8us,
//      R14 lifetime-disjoint workspace). 5 launches.

typedef __hip_bfloat16 bf16;
typedef __attribute__((ext_vector_type(8))) short bf16x8;
typedef __attribute__((ext_vector_type(4))) float f32x4;

#define MFMA_BF16(a, b, c) __builtin_amdgcn_mfma_f32_16x16x32_bf16((a), (b), (c), 0, 0, 0)

__device__ __forceinline__ float us2f(unsigned short u) {
  unsigned int v = ((unsigned int)u) << 16;
  return __builtin_bit_cast(float, v);
}

__device__ __forceinline__ unsigned pack_bf16x2(float a, float b) {  // RNE (epilogues)
  union { __hip_bfloat162 h; unsigned u; } cv;
  cv.h = __float22bfloat162_rn(float2{a, b});
  return cv.u;
}

__device__ __forceinline__ unsigned pack_bf16x2_trunc(float a, float b) {  // 1x v_perm
  return __builtin_amdgcn_perm(__builtin_bit_cast(unsigned, b),
                               __builtin_bit_cast(unsigned, a), 0x07060302u);
}

// async global->LDS, 16B per lane; lane i's dest = wave-uniform base + i*16
__device__ __forceinline__ void gl_lds16(const bf16* g, bf16* l) {
  __builtin_amdgcn_global_load_lds(
      (const __attribute__((address_space(1))) void*)g,
      (__attribute__((address_space(3))) void*)l, 16, 0, 0);
}

// raw barrier + compile-time scheduling fence: nothing (esp. plain LDS
// loads) may move across this sync point in either direction.
__device__ __forceinline__ void barrier_pinned() {
  __builtin_amdgcn_s_barrier();
  __builtin_amdgcn_sched_barrier(0);
}

// m204 bijective XCD swizzle; requires nwg % 8 == 0.
__device__ __forceinline__ int xcd_swz(int orig, int nwg) {
  return (orig & 7) * (nwg >> 3) + (orig >> 3);
}

// ---------------- wave-per-row LayerNorm core (D=1024, no LDS/barriers) ----------------
// Lane handles elements lane*4 + j*256 (j=0..3): every load/store
// instruction covers a dense 512B-1KB span across the wave.
template <typename TIN>
__device__ __forceinline__ void ln_wave(
    const TIN* __restrict__ in, const float* __restrict__ gamma,
    const float* __restrict__ beta, bf16* __restrict__ out,
    int stride, float sc, int row)
{
  const int lane = threadIdx.x & 63;
  const TIN* rp = in + (size_t)row * stride;
  float x[16];
#pragma unroll
  for (int j = 0; j < 4; ++j) {
    if constexpr (std::is_same_v<TIN, float>) {
      float4 u = *(const float4*)(rp + j * 256 + lane * 4);
      x[j * 4 + 0] = u.x; x[j * 4 + 1] = u.y;
      x[j * 4 + 2] = u.z; x[j * 4 + 3] = u.w;
    } else {
      ushort4 u = *(const ushort4*)(rp + j * 256 + lane * 4);
      x[j * 4 + 0] = us2f(u.x); x[j * 4 + 1] = us2f(u.y);
      x[j * 4 + 2] = us2f(u.z); x[j * 4 + 3] = us2f(u.w);
    }
  }
  float s = 0.0f, s2 = 0.0f;
#pragma unroll
  for (int i = 0; i < 16; ++i) { s += x[i]; s2 += x[i] * x[i]; }
#pragma unroll
  for (int m = 1; m < 64; m <<= 1) {
    s += __shfl_xor(s, m);
    s2 += __shfl_xor(s2, m);
  }
  const float mu = s * (1.0f / 1024.0f);
  const float rs = rsqrtf(s2 * (1.0f / 1024.0f) - mu * mu + 1e-5f);
  bf16* op = out + (size_t)row * 1024;
#pragma unroll
  for (int j = 0; j < 4; ++j) {
    float4 g4 = *(const float4*)(gamma + j * 256 + lane * 4);
    float4 b4 = *(const float4*)(beta + j * 256 + lane * 4);
    uint2 o;
    o.x = pack_bf16x2(((x[j * 4 + 0] - mu) * rs * g4.x + b4.x) * sc,
                      ((x[j * 4 + 1] - mu) * rs * g4.y + b4.y) * sc);
    o.y = pack_bf16x2(((x[j * 4 + 2] - mu) * rs * g4.z + b4.z) * sc,
                      ((x[j * 4 + 3] - mu) * rs * g4.w + b4.w) * sc);
    *(uint2*)(op + j * 256 + lane * 4) = o;
  }
}

// ---------------- standalone LN pair (P3): 4 rows/block, wave-per-row ----------------
// lnid = bid*4 + wave in [0, 8192); row = lnid>>1, which = lnid&1.
template <typename TIN>
__global__ __launch_bounds__(256) void ln2_kernel(
    const TIN* __restrict__ in0, const TIN* __restrict__ in1, int stride,
    const float* __restrict__ g0, const float* __restrict__ b0,
    const float* __restrict__ g1, const float* __restrict__ b1,
    bf16* __restrict__ out0, bf16* __restrict__ out1,
    float sc0, float sc1)
{
  const int w = threadIdx.x >> 6;
  const int lnid = blockIdx.x * 4 + w;
  const int row = lnid >> 1, which = lnid & 1;
  ln_wave<TIN>(which ? in1 : in0, which ? g1 : g0, which ? b1 : b0,
               which ? out1 : out0, stride, which ? sc1 : sc0, row);
}

// ---------------- 64x64 f32->bf16 transpose tile core ----------------
__device__ __forceinline__ void transpose_core(
    const float* __restrict__ in, bf16* __restrict__ out, int C,
    int r0, int c0, float (*tile)[68])
{
  const int R = 1024;
  const int t = threadIdx.x;
  const int lr = t >> 2, lc = (t & 3) * 16;
  const float* src = in + (size_t)(r0 + lr) * C + (c0 + lc);
#pragma unroll
  for (int i = 0; i < 4; ++i) {
    float4 u = *(const float4*)(src + i * 4);
    tile[lr][lc + i * 4 + 0] = u.x;
    tile[lr][lc + i * 4 + 1] = u.y;
    tile[lr][lc + i * 4 + 2] = u.z;
    tile[lr][lc + i * 4 + 3] = u.w;
  }
  __syncthreads();
  __align__(16) bf16 tmp[16];
#pragma unroll
  for (int j = 0; j < 16; ++j) tmp[j] = __float2bfloat16(tile[lc + j][lr]);
  bf16* dst = out + (size_t)(c0 + lr) * R + (r0 + lc);
  *(bf16x8*)dst       = *(const bf16x8*)&tmp[0];
  *(bf16x8*)(dst + 8) = *(const bf16x8*)&tmp[8];
}

// ---------------- prep: input LNs (2048 blocks, wave-per-row) + 3 weight transposes (1024) ----------------
__global__ __launch_bounds__(256) void prep_kernel(
    const float* __restrict__ keys, const float* __restrict__ values,
    const float* __restrict__ qk_g, const float* __restrict__ qk_b,
    const float* __restrict__ val_g, const float* __restrict__ val_b,
    bf16* __restrict__ keys_ln, bf16* __restrict__ values_ln,
    const float* __restrict__ w_qk, bf16* __restrict__ wqkT,
    const float* __restrict__ w_v, bf16* __restrict__ wvT,
    const float* __restrict__ w_out, bf16* __restrict__ woutT)
{
  __shared__ float tile[64][68];
  const int bid = blockIdx.x;
  if (bid < 2048) {
    const int w = threadIdx.x >> 6;
    const int lnid = bid * 4 + w;            // [0, 8192)
    const int row = lnid >> 1, which = lnid & 1;
    ln_wave<float>(which ? values : keys, which ? val_g : qk_g,
                   which ? val_b : qk_b, which ? values_ln : keys_ln,
                   1024, 1.0f, row);
  } else {
    const int tz = bid - 2048;
    if (tz < 512) {
      transpose_core(w_qk, wqkT, 2048, (tz >> 5) * 64, (tz & 31) * 64, tile);
    } else if (tz < 768) {
      const int s = tz - 512;
      transpose_core(w_v, wvT, 1024, (s >> 4) * 64, (s & 15) * 64, tile);
    } else {
      const int s = tz - 768;
      transpose_core(w_out, woutT, 1024, (s >> 4) * 64, (s & 15) * 64, tile);
    }
  }
}

// ---------------- GEMM core: C(M,N) = A(M,K) @ Bt(N,K)^T (+bias), bf16 in, fp32 accum ----------------
// BK=64, double-buffered K-loop with counted vmcnt (ASL+BSL loads stay in
// flight across the compute phase). XOR chunk swizzle (c ^ (row&7)) on
// 128B LDS rows -> conflict-free ds_read_b128 frags. 2x2 waves. All raw
// barriers are sched_barrier(0)-pinned so frag ds_reads cannot hoist into
// the staging/vmcnt window. TMODE 1: coalesced vt store via LDS bounce:
// vt[((row>>11)*1024 + col)*2048 + (row&2047)].
template <int BM, int BN, int TMODE, typename TOUT>
__device__ __forceinline__ void gemm_core(
    const bf16* __restrict__ A, const bf16* __restrict__ Bt,
    const float* __restrict__ bias, TOUT* __restrict__ C,
    int N, int K, int has_bias, int bx, int by, bf16* smem)
{
  constexpr int MT = BM / 32, NT = BN / 32;     // 16x16 frags per wave
  constexpr int ASL = BM / 32, BSL = BN / 32;   // 16B staging slots per thread (BK=64)
  constexpr int BUFE = (BM + BN) * 64;          // elements per buffer
  const int t = threadIdx.x;
  const int w = t >> 6, lane = t & 63, l15 = lane & 15, quad = lane >> 4;
  const int wy = w >> 1, wx = w & 1;
  const bf16* Ab = A + (size_t)by * BM * K;
  const bf16* Bb = Bt + (size_t)bx * BN * K;
  f32x4 acc[MT][NT] = {};

  // per-thread staging sources, hoisted out of the K-loop (addr-mul once)
  const bf16* aptr[ASL];
  const bf16* bptr[BSL];
#pragma unroll
  for (int i = 0; i < ASL; ++i) {
    int s = i * 256 + t, row = s >> 3, c = (s & 7) ^ (row & 7);
    aptr[i] = Ab + (size_t)row * K + (c << 3);
  }
#pragma unroll
  for (int i = 0; i < BSL; ++i) {
    int s = i * 256 + t, row = s >> 3, c = (s & 7) ^ (row & 7);
    bptr[i] = Bb + (size_t)row * K + (c << 3);
  }

  auto stage = [&](bf16* buf, int kc) {
#pragma unroll
    for (int i = 0; i < ASL; ++i)
      gl_lds16(aptr[i] + kc, buf + (i * 256 + t) * 8);
#pragma unroll
    for (int i = 0; i < BSL; ++i)
      gl_lds16(bptr[i] + kc, buf + BM * 64 + (i * 256 + t) * 8);
  };

  const int sw = (quad ^ (l15 & 7)) << 3;
  const int NK = K >> 6;

  stage(smem, 0);  // prologue: tile 0 into buf 0

  for (int kt = 0; kt < NK; ++kt) {
    const int cur = kt & 1;
    bf16* lA = smem + cur * BUFE;
    bf16* lB = lA + BM * 64;
    barrier_pinned();  // all waves done reading buf cur^1
    if (kt + 1 < NK) {
      stage(smem + (cur ^ 1) * BUFE, (kt + 1) << 6);
      if constexpr (ASL + BSL == 8)
        asm volatile("s_waitcnt vmcnt(8)" ::: "memory");  // tile kt landed; kt+1 in flight
      else if constexpr (ASL + BSL == 6)
        asm volatile("s_waitcnt vmcnt(6)" ::: "memory");
      else
        asm volatile("s_waitcnt vmcnt(4)" ::: "memory");
    } else {
      asm volatile("s_waitcnt vmcnt(0)" ::: "memory");
    }
    barrier_pinned();  // staged data visible to all waves; reads pinned below

#pragma unroll
    for (int h = 0; h < 2; ++h) {
      const int so = sw ^ (h << 5);
      bf16x8 af[MT], bfr[NT];
#pragma unroll
      for (int mt = 0; mt < MT; ++mt)
        af[mt] = *(const bf16x8*)&lA[(wy * (BM / 2) + mt * 16 + l15) * 64 + so];
#pragma unroll
      for (int nt = 0; nt < NT; ++nt)
        bfr[nt] = *(const bf16x8*)&lB[(wx * (BN / 2) + nt * 16 + l15) * 64 + so];
#pragma unroll
      for (int mt = 0; mt < MT; ++mt)
#pragma unroll
        for (int nt = 0; nt < NT; ++nt)
          acc[mt][nt] = MFMA_BF16(af[mt], bfr[nt], acc[mt][nt]);
    }
  }

  if constexpr (TMODE == 1) {
    // acc: row n = wy*(BM/2)+mt*16+quad*4+r, col d = wx*(BN/2)+nt*16+l15 -> lOut[d][n]
    constexpr int STR = BM + 8;   // keeps d*STR*2 bytes 16B-aligned
    static_assert(BN * STR <= 2 * BUFE, "lOut must fit staging buffers");
    bf16* lOut = smem;            // aliases dead staging buffers
    __syncthreads();
#pragma unroll
    for (int mt = 0; mt < MT; ++mt)
#pragma unroll
      for (int nt = 0; nt < NT; ++nt) {
        const int d = wx * (BN / 2) + nt * 16 + l15;
        const int n = wy * (BM / 2) + mt * 16 + quad * 4;
        uint2 pk;
        pk.x = pack_bf16x2(acc[mt][nt][0], acc[mt][nt][1]);
        pk.y = pack_bf16x2(acc[mt][nt][2], acc[mt][nt][3]);
        *(uint2*)&lOut[d * STR + n] = pk;
      }
    __syncthreads();
    const int row0 = by * BM;
    const int bidx = row0 >> 11, n0 = row0 & 2047;
    const int col0 = bx * BN;
    constexpr int CPR = BM / 32;                  // 32-el chunks per d-row
    constexpr int NITER = (BN * CPR) / 256;
#pragma unroll
    for (int it = 0; it < NITER; ++it) {
      const int idx = it * 256 + t;
      const int d = idx / CPR, off = (idx % CPR) * 32;
      const bf16* srcp = &lOut[d * STR + off];
      bf16* g = (bf16*)C + ((size_t)(bidx << 10) + col0 + d) * 2048 + n0 + off;
#pragma unroll
      for (int j = 0; j < 4; ++j)
        *(bf16x8*)(g + j * 8) = *(const bf16x8*)(srcp + j * 8);
    }
  } else {
    const int row_base = by * BM + wy * (BM / 2);
    const int col_base = bx * BN + wx * (BN / 2);
#pragma unroll
    for (int mt = 0; mt < MT; ++mt)
#pragma unroll
      for (int nt = 0; nt < NT; ++nt) {
        const int col = col_base + nt * 16 + l15;
        const float bb = has_bias ? bias[col] : 0.0f;
#pragma unroll
        for (int r = 0; r < 4; ++r) {
          const int row = row_base + mt * 16 + quad * 4 + r;
          float v = acc[mt][nt][r] + bb;
          if constexpr (std::is_same_v<TOUT, bf16>)
            C[(size_t)row * N + col] = __float2bfloat16(v);
          else
            C[(size_t)row * N + col] = v;
        }
      }
  }
}

// single-GEMM wrapper (P5) with flattened XCD swizzle (nwg % 8 == 0)
template <int BM, int BN, int TMODE, typename TOUT>
__global__ __launch_bounds__(256) void gemm_bt_kernel(
    const bf16* __restrict__ A, const bf16* __restrict__ Bt,
    const float* __restrict__ bias, TOUT* __restrict__ C,
    int N, int K, int has_bias)
{
  __shared__ __align__(16) bf16 smem[2 * (BM + BN) * 64];
  const int nwg = gridDim.x * gridDim.y;
  const int orig = blockIdx.y * gridDim.x + blockIdx.x;
  const int s = xcd_swz(orig, nwg);
  gemm_core<BM, BN, TMODE, TOUT>(A, Bt, bias, C, N, K, has_bias,
                                 s % gridDim.x, s / gridDim.x, smem);
}

// dual GEMM (P2): qk = keys_ln @ wqkT (1024 blocks, 128x64) +
//                 vt = values_ln @ wvT (512 blocks, 128x64, TMODE1)
// NOTE: qk and vt must be DISJOINT workspace regions (concurrent in one
// dispatch) — enforced by the R14 workspace map. XCD swizzle per segment.
__global__ __launch_bounds__(256) void gemm_dual_kernel(
    const bf16* __restrict__ A0, const bf16* __restrict__ B0, bf16* __restrict__ C0,
    const bf16* __restrict__ A1, const bf16* __restrict__ B1, bf16* __restrict__ C1)
{
  __shared__ __align__(16) bf16 smem[2 * 192 * 64];  // 48KB -> 3 blocks/CU
  const int bid = blockIdx.x;
  if (bid < 1024) {
    const int s = xcd_swz(bid, 1024);
    gemm_core<128, 64, 0, bf16>(A0, B0, nullptr, C0, 2048, 1024, 0,
                                s & 31, s >> 5, smem);
  } else {
    const int s = xcd_swz(bid - 1024, 512);
    gemm_core<128, 64, 1, bf16>(A1, B1, nullptr, C1, 1024, 1024, 0,
                                s & 15, s >> 4, smem);
  }
}

// ---------------- Flash attention (R17-exact): 2-subtile pipeline + in-register P + MFMA row sums ----------------
// P fully in-register via K-row permutation: LDS slot s (bits n1 n0 q1 q0
// r1 r0) holds global K row g(s) = (n1 q1 q0 n0 r1 r0) within each 64-row
// granule, so the QK^T C/D fragment, exp'd and packed, IS the 16x16x32 PV
// B-operand (col=l15, k=quad*8..+7). 16 iterations stage a 128-row K/V tile
// (two 64-row sub-tiles) per pinned-barrier pair with vmcnt(8). Row sums
// via ones-A MFMA. XCD-affine (b,h) grouping — flat 512-block grid,
// bh = (bid&7) + 8*(bid>>7), qt = (bid>>3)&15: all 16 q-tiles of one (b,h)
// on the same XCD under round-robin dispatch -> 512KB K/V panel stays
// L2-resident (verified: FETCH 73.8 -> 12.3MB). Best measured: 47.8us.
__global__ __launch_bounds__(256) void flash_kernel(
    const bf16* __restrict__ Q, const bf16* __restrict__ Km,
    const bf16* __restrict__ Vt, bf16* __restrict__ O)
{
  __shared__ __align__(16) bf16 smem[8192 + 16384 + 16384];  // 80KB; 2 blocks/CU (grid-limited anyway)
  bf16* lQ = smem;                  // 128x64
  bf16* lKb = smem + 8192;          // 2 x (2 x 64x64)
  bf16* lVb = smem + 8192 + 16384;  // 2 x (2 x 64x64)
  const int t = threadIdx.x;
  const int w = t >> 6, lane = t & 63, l15 = lane & 15, quad = lane >> 4;
  const int bid = blockIdx.x;
  const int qt = (bid >> 3) & 15;               // q-tile within (b,h)
  const int bh = (bid & 7) + ((bid >> 7) << 3); // XCD-affine (b,h) group
  const int b = bh >> 4, h = bh & 15;
  const int qrow0 = b * 2048 + qt * 128;
  const bf16* qbase = Q + (size_t)qrow0 * 1024 + h * 64;
  const bf16* kbase = Km + ((size_t)(b * 2048)) * 1024 + h * 64;
  const bf16* vbase = Vt + ((size_t)(b * 1024 + h * 64)) * 2048;

  const int sr0 = t >> 3, sc0 = ((t & 7) ^ (sr0 & 7)) << 3;
  const int sr1 = (256 + t) >> 3, sc1 = (((256 + t) & 7) ^ (sr1 & 7)) << 3;
  // K-row permutation g(s): (n1 n0 q1 q0 r1 r0) -> (n1 q1 q0 n0 r1 r0)
  const int gr0 = (sr0 & 0x23) | ((sr0 & 0x0C) << 1) | ((sr0 & 0x10) >> 2);
  const int gr1 = (sr1 & 0x23) | ((sr1 & 0x0C) << 1) | ((sr1 & 0x10) >> 2);
  const bf16* kp0 = kbase + gr0 * 1024 + sc0;
  const bf16* kp1 = kbase + gr1 * 1024 + sc1;
  const bf16* vp0 = vbase + sr0 * 2048 + sc0;
  const bf16* vp1 = vbase + sr1 * 2048 + sc1;

  // stage one 64-row K sub-tile (rows kro..+63) and 64-col V sub-tile into dst
  auto stage_kv = [&](bf16* kdst, bf16* vdst, int kro, int vco) {
    const int ko = kro << 10;  // kro * 1024
    gl_lds16(kp0 + ko, kdst + t * 8);
    gl_lds16(kp1 + ko, kdst + (256 + t) * 8);
    gl_lds16(vp0 + vco, vdst + t * 8);
    gl_lds16(vp1 + vco, vdst + (256 + t) * 8);
  };

  // prologue: stage Q (4) + K/V tile 0 (8: two sub-tiles)
#pragma unroll
  for (int i = 0; i < 4; ++i) {
    int s = i * 256 + t;
    int row = s >> 3, c = (s & 7) ^ (row & 7);
    gl_lds16(qbase + (size_t)row * 1024 + (c << 3), lQ + s * 8);
  }
  stage_kv(lKb, lVb, 0, 0);
  stage_kv(lKb + 4096, lVb + 4096, 64, 64);
  asm volatile("s_waitcnt vmcnt(8)" ::: "memory");  // Q done (in-order); tile0 in flight
  barrier_pinned();

  const int sw = (quad ^ (l15 & 7)) << 3;
  bf16x8 qf[2][2];
#pragma unroll
  for (int mset = 0; mset < 2; ++mset) {
    const int row = w * 32 + mset * 16 + l15;
    qf[mset][0] = *(const bf16x8*)&lQ[row * 64 + sw];
    qf[mset][1] = *(const bf16x8*)&lQ[row * 64 + (sw ^ 32)];
  }

  f32x4 o_acc[4][2] = {};   // [dt][mset]: O^T row d = dt*16+quad*4+r, col m = mset*16+l15
  f32x4 s_acc[2] = {};      // ones-MFMA row sums (all rows identical per lane col)
  const short ONEB = (short)0x3F80;  // bf16 1.0
  const bf16x8 ones = {ONEB, ONEB, ONEB, ONEB, ONEB, ONEB, ONEB, ONEB};

  for (int kt = 0; kt < 16; ++kt) {
    const int cur = kt & 1;
    bf16* lK = lKb + cur * 8192;
    bf16* lV = lVb + cur * 8192;
    bf16* lKn = lKb + (cur ^ 1) * 8192;
    bf16* lVn = lVb + (cur ^ 1) * 8192;

    barrier_pinned();  // all waves done reading buf cur^1
    {
      const int ktn = (kt + 1) & 15;  // wrap: restage tile 0 into dead buf
      const int kro = ktn << 7;       // ktn*128 K-rows
      const int vco = ktn << 7;       // ktn*128 V-cols
      stage_kv(lKn, lVn, kro, vco);
      stage_kv(lKn + 4096, lVn + 4096, kro + 64, vco + 64);
    }
    asm volatile("s_waitcnt vmcnt(8)" ::: "memory");  // current tile landed; next in flight
    barrier_pinned();  // tile kt visible to all waves; sub-tile reads pinned below

#pragma unroll
    for (int sub = 0; sub < 2; ++sub) {
      bf16* lKs = lK + sub * 4096;
      bf16* lVs = lV + sub * 4096;

      bf16x8 kf[4][2];
#pragma unroll
      for (int nt = 0; nt < 4; ++nt) {
        kf[nt][0] = *(const bf16x8*)&lKs[(nt * 16 + l15) * 64 + sw];
        kf[nt][1] = *(const bf16x8*)&lKs[(nt * 16 + l15) * 64 + (sw ^ 32)];
      }

      // S^T (log2-domain) + v_exp + truncating pack straight into B-operand regs
      bf16x8 pa[2][2];
#pragma unroll
      for (int mset = 0; mset < 2; ++mset) {
#pragma unroll
        for (int half = 0; half < 2; ++half) {
          f32x4 z0 = {}, z1 = {};
          z0 = MFMA_BF16(kf[2 * half + 0][0], qf[mset][0], z0);
          z0 = MFMA_BF16(kf[2 * half + 0][1], qf[mset][1], z0);
          z1 = MFMA_BF16(kf[2 * half + 1][0], qf[mset][0], z1);
          z1 = MFMA_BF16(kf[2 * half + 1][1], qf[mset][1], z1);
          f32x4 p0, p1;
#pragma unroll
          for (int r = 0; r < 4; ++r) {
            p0[r] = __builtin_amdgcn_exp2f(z0[r]);
            p1[r] = __builtin_amdgcn_exp2f(z1[r]);
          }
          union { unsigned u[4]; bf16x8 v; } cv;
          cv.u[0] = pack_bf16x2_trunc(p0[0], p0[1]);
          cv.u[1] = pack_bf16x2_trunc(p0[2], p0[3]);
          cv.u[2] = pack_bf16x2_trunc(p1[0], p1[1]);
          cv.u[3] = pack_bf16x2_trunc(p1[2], p1[3]);
          pa[mset][half] = cv.v;
        }
      }

      bf16x8 vf[4][2];
#pragma unroll
      for (int dt = 0; dt < 4; ++dt) {
        vf[dt][0] = *(const bf16x8*)&lVs[(dt * 16 + l15) * 64 + sw];
        vf[dt][1] = *(const bf16x8*)&lVs[(dt * 16 + l15) * 64 + (sw ^ 32)];
      }

      __builtin_amdgcn_s_setprio(1);
#pragma unroll
      for (int mset = 0; mset < 2; ++mset) {
        s_acc[mset] = MFMA_BF16(ones, pa[mset][0], s_acc[mset]);
        s_acc[mset] = MFMA_BF16(ones, pa[mset][1], s_acc[mset]);
#pragma unroll
        for (int dt = 0; dt < 4; ++dt) {
          o_acc[dt][mset] = MFMA_BF16(vf[dt][0], pa[mset][0], o_acc[dt][mset]);
          o_acc[dt][mset] = MFMA_BF16(vf[dt][1], pa[mset][1], o_acc[dt][mset]);
        }
      }
      __builtin_amdgcn_s_setprio(0);
    }
  }

  // epilogue: divide + store O^T fragments (row sum already complete per lane)
#pragma unroll
  for (int mset = 0; mset < 2; ++mset) {
    const float inv = 1.0f / s_acc[mset][0];
    const int m = qrow0 + w * 32 + mset * 16 + l15;
#pragma unroll
    for (int dt = 0; dt < 4; ++dt) {
      uint2 ok;
      ok.x = pack_bf16x2(o_acc[dt][mset][0] * inv, o_acc[dt][mset][1] * inv);
      ok.y = pack_bf16x2(o_acc[dt][mset][2] * inv, o_acc[dt][mset][3] * inv);
      *(uint2*)&O[(size_t)m * 1024 + h * 64 + dt * 16 + quad * 4] = ok;
    }
  }
}

extern "C" void kernel_launch(void* const* d_in, const int* in_sizes, int n_in,
                              void* d_out, int out_size, void* d_ws, size_t ws_size,
                              hipStream_t stream)
{
  (void)in_sizes; (void)n_in; (void)out_size; (void)ws_size;
  const float* keys   = (const float*)d_in[0];
  const float* values = (const float*)d_in[1];
  const float* qk_g   = (const float*)d_in[2];
  const float* qk_b   = (const float*)d_in[3];
  const float* val_g  = (const float*)d_in[4];
  const float* val_b  = (const float*)d_in[5];
  const float* key_g  = (const float*)d_in[6];
  const float* key_b  = (const float*)d_in[7];
  const float* qry_g  = (const float*)d_in[8];
  const float* qry_b  = (const float*)d_in[9];
  const float* w_qk   = (const float*)d_in[10];
  const float* w_v    = (const float*)d_in[11];
  const float* w_out  = (const float*)d_in[12];
  const float* b_out  = (const float*)d_in[13];
  float* out = (float*)d_out;

  const float CEXP = 0.03125f * 1.44269504f;  // ID^-0.5 * log2(e), folded into q-LN

  // R14 workspace map (48MB) — lifetime-disjoint under the merged schedule.
  // P1: prep (writes keys_ln, values_ln, weights)
  // P2: dual GEMM (reads keys_ln/values_ln/wqkT/wvT; writes qk, vt — DISJOINT)
  // P3: q/k LN (reads qk; writes qln over keys_ln, kln over values_ln — both dead)
  // P4: flash (reads qln/kln/vt; writes attn over qk[0:8MB] — qk dead)
  // P5: out GEMM (reads attn/woutT; writes d_out)
  char* ws = (char*)d_ws;
  const size_t MB = 1024 * 1024;
  bf16* keys_ln   = (bf16*)(ws + 0);        // 8MB   P1w, P2r
  bf16* values_ln = (bf16*)(ws + 8 * MB);   // 8MB   P1w, P2r
  bf16* qk        = (bf16*)(ws + 16 * MB);  // 16MB  P2w, P3r
  bf16* vt        = (bf16*)(ws + 32 * MB);  // 8MB   P2w, P4r
  bf16* qln       = (bf16*)(ws + 0);        // 8MB   P3w, P4r (reuses keys_ln)
  bf16* kln       = (bf16*)(ws + 8 * MB);   // 8MB   P3w, P4r (reuses values_ln)
  bf16* attn      = (bf16*)(ws + 16 * MB);  // 8MB   P4w, P5r (reuses qk)
  bf16* wqkT      = (bf16*)(ws + 40 * MB);  // 4MB   P1w, P2r
  bf16* wvT       = (bf16*)(ws + 44 * MB);  // 2MB   P1w, P2r
  bf16* woutT     = (bf16*)(ws + 46 * MB);  // 2MB   P1w, P5r

  // P1: input layernorms (wave-per-row, 2048 blocks) + weight transposes (1024 blocks)
  prep_kernel<<<dim3(3072), 256, 0, stream>>>(
      keys, values, qk_g, qk_b, val_g, val_b, keys_ln, values_ln,
      w_qk, wqkT, w_v, wvT, w_out, woutT);
  // P2: qk = keys_ln @ w_qk (1024 blocks) + vt = values_ln @ w_v transposed (512 blocks)
  gemm_dual_kernel<<<dim3(1536), 256, 0, stream>>>(
      keys_ln, wqkT, qk, values_ln, wvT, vt);
  // P3: q/k layernorms (wave-per-row, 2048 blocks); qln pre-scaled by CEXP
  ln2_kernel<bf16><<<dim3(2048), 256, 0, stream>>>(
      qk, qk + 1024, 2048, qry_g, qry_b, key_g, key_b, qln, kln, CEXP, 1.0f);
  // P4: flash attention -> attn (flat 512-block grid, XCD-affine bh grouping)
  flash_kernel<<<dim3(512), 256, 0, stream>>>(qln, kln, vt, attn);
  // P5: out = attn @ w_out + b_out (fp32 out), 128x64 tile, 512 blocks, 3 blocks/CU
  gemm_bt_kernel<128, 64, 0, float><<<dim3(16, 32), 256, 0, stream>>>(
      attn, woutT, b_out, out, 1024, 1024, 1);
}

// Round 14
// 208.871 us; speedup vs baseline: 1.0704x; 1.0077x over previous
//
#include <hip/hip_runtime.h>
#include <hip/hip_bf16.h>
#include <type_traits>

// SelfAttention fused block, MI355X/gfx950.
// R23: close the last unmeasured tile cell. R16 changed qk-tile AND added
//      the XCD swizzle together; 128x128-with-swizzle was never measured.
//      Mechanism: per K-step a 128x128 block stages 32KB for 2x the output
//      of 128x64 (33% less L2 staging traffic dispatch-wide; MFMA:ds_read
//      2.0 vs 1.33) at 2 blocks/CU vs 3. P2 dual -> qk 128x128 (512 blk)
//      + vt 128x128 TMODE1 (256 blk), 64KB LDS, per-segment swizzle.
//      Everything else byte-identical to R22 (best: 210.5us — wave-per-row
//      LNs, flash R17-exact 47.8us, P5 128x64@3/CU, R14 workspace map).
//      5 launches.

typedef __hip_bfloat16 bf16;
typedef __attribute__((ext_vector_type(8))) short bf16x8;
typedef __attribute__((ext_vector_type(4))) float f32x4;

#define MFMA_BF16(a, b, c) __builtin_amdgcn_mfma_f32_16x16x32_bf16((a), (b), (c), 0, 0, 0)

__device__ __forceinline__ float us2f(unsigned short u) {
  unsigned int v = ((unsigned int)u) << 16;
  return __builtin_bit_cast(float, v);
}

__device__ __forceinline__ unsigned pack_bf16x2(float a, float b) {  // RNE (epilogues)
  union { __hip_bfloat162 h; unsigned u; } cv;
  cv.h = __float22bfloat162_rn(float2{a, b});
  return cv.u;
}

__device__ __forceinline__ unsigned pack_bf16x2_trunc(float a, float b) {  // 1x v_perm
  return __builtin_amdgcn_perm(__builtin_bit_cast(unsigned, b),
                               __builtin_bit_cast(unsigned, a), 0x07060302u);
}

// async global->LDS, 16B per lane; lane i's dest = wave-uniform base + i*16
__device__ __forceinline__ void gl_lds16(const bf16* g, bf16* l) {
  __builtin_amdgcn_global_load_lds(
      (const __attribute__((address_space(1))) void*)g,
      (__attribute__((address_space(3))) void*)l, 16, 0, 0);
}

// raw barrier + compile-time scheduling fence: nothing (esp. plain LDS
// loads) may move across this sync point in either direction.
__device__ __forceinline__ void barrier_pinned() {
  __builtin_amdgcn_s_barrier();
  __builtin_amdgcn_sched_barrier(0);
}

// m204 bijective XCD swizzle; requires nwg % 8 == 0.
__device__ __forceinline__ int xcd_swz(int orig, int nwg) {
  return (orig & 7) * (nwg >> 3) + (orig >> 3);
}

// ---------------- wave-per-row LayerNorm core (D=1024, no LDS/barriers) ----------------
// Lane handles elements lane*4 + j*256 (j=0..3): every load/store
// instruction covers a dense 512B-1KB span across the wave.
template <typename TIN>
__device__ __forceinline__ void ln_wave(
    const TIN* __restrict__ in, const float* __restrict__ gamma,
    const float* __restrict__ beta, bf16* __restrict__ out,
    int stride, float sc, int row)
{
  const int lane = threadIdx.x & 63;
  const TIN* rp = in + (size_t)row * stride;
  float x[16];
#pragma unroll
  for (int j = 0; j < 4; ++j) {
    if constexpr (std::is_same_v<TIN, float>) {
      float4 u = *(const float4*)(rp + j * 256 + lane * 4);
      x[j * 4 + 0] = u.x; x[j * 4 + 1] = u.y;
      x[j * 4 + 2] = u.z; x[j * 4 + 3] = u.w;
    } else {
      ushort4 u = *(const ushort4*)(rp + j * 256 + lane * 4);
      x[j * 4 + 0] = us2f(u.x); x[j * 4 + 1] = us2f(u.y);
      x[j * 4 + 2] = us2f(u.z); x[j * 4 + 3] = us2f(u.w);
    }
  }
  float s = 0.0f, s2 = 0.0f;
#pragma unroll
  for (int i = 0; i < 16; ++i) { s += x[i]; s2 += x[i] * x[i]; }
#pragma unroll
  for (int m = 1; m < 64; m <<= 1) {
    s += __shfl_xor(s, m);
    s2 += __shfl_xor(s2, m);
  }
  const float mu = s * (1.0f / 1024.0f);
  const float rs = rsqrtf(s2 * (1.0f / 1024.0f) - mu * mu + 1e-5f);
  bf16* op = out + (size_t)row * 1024;
#pragma unroll
  for (int j = 0; j < 4; ++j) {
    float4 g4 = *(const float4*)(gamma + j * 256 + lane * 4);
    float4 b4 = *(const float4*)(beta + j * 256 + lane * 4);
    uint2 o;
    o.x = pack_bf16x2(((x[j * 4 + 0] - mu) * rs * g4.x + b4.x) * sc,
                      ((x[j * 4 + 1] - mu) * rs * g4.y + b4.y) * sc);
    o.y = pack_bf16x2(((x[j * 4 + 2] - mu) * rs * g4.z + b4.z) * sc,
                      ((x[j * 4 + 3] - mu) * rs * g4.w + b4.w) * sc);
    *(uint2*)(op + j * 256 + lane * 4) = o;
  }
}

// ---------------- standalone LN pair (P3): 4 rows/block, wave-per-row ----------------
// lnid = bid*4 + wave in [0, 8192); row = lnid>>1, which = lnid&1.
template <typename TIN>
__global__ __launch_bounds__(256) void ln2_kernel(
    const TIN* __restrict__ in0, const TIN* __restrict__ in1, int stride,
    const float* __restrict__ g0, const float* __restrict__ b0,
    const float* __restrict__ g1, const float* __restrict__ b1,
    bf16* __restrict__ out0, bf16* __restrict__ out1,
    float sc0, float sc1)
{
  const int w = threadIdx.x >> 6;
  const int lnid = blockIdx.x * 4 + w;
  const int row = lnid >> 1, which = lnid & 1;
  ln_wave<TIN>(which ? in1 : in0, which ? g1 : g0, which ? b1 : b0,
               which ? out1 : out0, stride, which ? sc1 : sc0, row);
}

// ---------------- 64x64 f32->bf16 transpose tile core ----------------
__device__ __forceinline__ void transpose_core(
    const float* __restrict__ in, bf16* __restrict__ out, int C,
    int r0, int c0, float (*tile)[68])
{
  const int R = 1024;
  const int t = threadIdx.x;
  const int lr = t >> 2, lc = (t & 3) * 16;
  const float* src = in + (size_t)(r0 + lr) * C + (c0 + lc);
#pragma unroll
  for (int i = 0; i < 4; ++i) {
    float4 u = *(const float4*)(src + i * 4);
    tile[lr][lc + i * 4 + 0] = u.x;
    tile[lr][lc + i * 4 + 1] = u.y;
    tile[lr][lc + i * 4 + 2] = u.z;
    tile[lr][lc + i * 4 + 3] = u.w;
  }
  __syncthreads();
  __align__(16) bf16 tmp[16];
#pragma unroll
  for (int j = 0; j < 16; ++j) tmp[j] = __float2bfloat16(tile[lc + j][lr]);
  bf16* dst = out + (size_t)(c0 + lr) * R + (r0 + lc);
  *(bf16x8*)dst       = *(const bf16x8*)&tmp[0];
  *(bf16x8*)(dst + 8) = *(const bf16x8*)&tmp[8];
}

// ---------------- prep: input LNs (2048 blocks, wave-per-row) + 3 weight transposes (1024) ----------------
__global__ __launch_bounds__(256) void prep_kernel(
    const float* __restrict__ keys, const float* __restrict__ values,
    const float* __restrict__ qk_g, const float* __restrict__ qk_b,
    const float* __restrict__ val_g, const float* __restrict__ val_b,
    bf16* __restrict__ keys_ln, bf16* __restrict__ values_ln,
    const float* __restrict__ w_qk, bf16* __restrict__ wqkT,
    const float* __restrict__ w_v, bf16* __restrict__ wvT,
    const float* __restrict__ w_out, bf16* __restrict__ woutT)
{
  __shared__ float tile[64][68];
  const int bid = blockIdx.x;
  if (bid < 2048) {
    const int w = threadIdx.x >> 6;
    const int lnid = bid * 4 + w;            // [0, 8192)
    const int row = lnid >> 1, which = lnid & 1;
    ln_wave<float>(which ? values : keys, which ? val_g : qk_g,
                   which ? val_b : qk_b, which ? values_ln : keys_ln,
                   1024, 1.0f, row);
  } else {
    const int tz = bid - 2048;
    if (tz < 512) {
      transpose_core(w_qk, wqkT, 2048, (tz >> 5) * 64, (tz & 31) * 64, tile);
    } else if (tz < 768) {
      const int s = tz - 512;
      transpose_core(w_v, wvT, 1024, (s >> 4) * 64, (s & 15) * 64, tile);
    } else {
      const int s = tz - 768;
      transpose_core(w_out, woutT, 1024, (s >> 4) * 64, (s & 15) * 64, tile);
    }
  }
}

// ---------------- GEMM core: C(M,N) = A(M,K) @ Bt(N,K)^T (+bias), bf16 in, fp32 accum ----------------
// BK=64, double-buffered K-loop with counted vmcnt (ASL+BSL loads stay in
// flight across the compute phase). XOR chunk swizzle (c ^ (row&7)) on
// 128B LDS rows -> conflict-free ds_read_b128 frags. 2x2 waves. All raw
// barriers are sched_barrier(0)-pinned so frag ds_reads cannot hoist into
// the staging/vmcnt window. TMODE 1: coalesced vt store via LDS bounce:
// vt[((row>>11)*1024 + col)*2048 + (row&2047)].
template <int BM, int BN, int TMODE, typename TOUT>
__device__ __forceinline__ void gemm_core(
    const bf16* __restrict__ A, const bf16* __restrict__ Bt,
    const float* __restrict__ bias, TOUT* __restrict__ C,
    int N, int K, int has_bias, int bx, int by, bf16* smem)
{
  constexpr int MT = BM / 32, NT = BN / 32;     // 16x16 frags per wave
  constexpr int ASL = BM / 32, BSL = BN / 32;   // 16B staging slots per thread (BK=64)
  constexpr int BUFE = (BM + BN) * 64;          // elements per buffer
  const int t = threadIdx.x;
  const int w = t >> 6, lane = t & 63, l15 = lane & 15, quad = lane >> 4;
  const int wy = w >> 1, wx = w & 1;
  const bf16* Ab = A + (size_t)by * BM * K;
  const bf16* Bb = Bt + (size_t)bx * BN * K;
  f32x4 acc[MT][NT] = {};

  // per-thread staging sources, hoisted out of the K-loop (addr-mul once)
  const bf16* aptr[ASL];
  const bf16* bptr[BSL];
#pragma unroll
  for (int i = 0; i < ASL; ++i) {
    int s = i * 256 + t, row = s >> 3, c = (s & 7) ^ (row & 7);
    aptr[i] = Ab + (size_t)row * K + (c << 3);
  }
#pragma unroll
  for (int i = 0; i < BSL; ++i) {
    int s = i * 256 + t, row = s >> 3, c = (s & 7) ^ (row & 7);
    bptr[i] = Bb + (size_t)row * K + (c << 3);
  }

  auto stage = [&](bf16* buf, int kc) {
#pragma unroll
    for (int i = 0; i < ASL; ++i)
      gl_lds16(aptr[i] + kc, buf + (i * 256 + t) * 8);
#pragma unroll
    for (int i = 0; i < BSL; ++i)
      gl_lds16(bptr[i] + kc, buf + BM * 64 + (i * 256 + t) * 8);
  };

  const int sw = (quad ^ (l15 & 7)) << 3;
  const int NK = K >> 6;

  stage(smem, 0);  // prologue: tile 0 into buf 0

  for (int kt = 0; kt < NK; ++kt) {
    const int cur = kt & 1;
    bf16* lA = smem + cur * BUFE;
    bf16* lB = lA + BM * 64;
    barrier_pinned();  // all waves done reading buf cur^1
    if (kt + 1 < NK) {
      stage(smem + (cur ^ 1) * BUFE, (kt + 1) << 6);
      if constexpr (ASL + BSL == 8)
        asm volatile("s_waitcnt vmcnt(8)" ::: "memory");  // tile kt landed; kt+1 in flight
      else if constexpr (ASL + BSL == 6)
        asm volatile("s_waitcnt vmcnt(6)" ::: "memory");
      else
        asm volatile("s_waitcnt vmcnt(4)" ::: "memory");
    } else {
      asm volatile("s_waitcnt vmcnt(0)" ::: "memory");
    }
    barrier_pinned();  // staged data visible to all waves; reads pinned below

#pragma unroll
    for (int h = 0; h < 2; ++h) {
      const int so = sw ^ (h << 5);
      bf16x8 af[MT], bfr[NT];
#pragma unroll
      for (int mt = 0; mt < MT; ++mt)
        af[mt] = *(const bf16x8*)&lA[(wy * (BM / 2) + mt * 16 + l15) * 64 + so];
#pragma unroll
      for (int nt = 0; nt < NT; ++nt)
        bfr[nt] = *(const bf16x8*)&lB[(wx * (BN / 2) + nt * 16 + l15) * 64 + so];
#pragma unroll
      for (int mt = 0; mt < MT; ++mt)
#pragma unroll
        for (int nt = 0; nt < NT; ++nt)
          acc[mt][nt] = MFMA_BF16(af[mt], bfr[nt], acc[mt][nt]);
    }
  }

  if constexpr (TMODE == 1) {
    // acc: row n = wy*(BM/2)+mt*16+quad*4+r, col d = wx*(BN/2)+nt*16+l15 -> lOut[d][n]
    constexpr int STR = BM + 8;   // keeps d*STR*2 bytes 16B-aligned
    static_assert(BN * STR <= 2 * BUFE, "lOut must fit staging buffers");
    bf16* lOut = smem;            // aliases dead staging buffers
    __syncthreads();
#pragma unroll
    for (int mt = 0; mt < MT; ++mt)
#pragma unroll
      for (int nt = 0; nt < NT; ++nt) {
        const int d = wx * (BN / 2) + nt * 16 + l15;
        const int n = wy * (BM / 2) + mt * 16 + quad * 4;
        uint2 pk;
        pk.x = pack_bf16x2(acc[mt][nt][0], acc[mt][nt][1]);
        pk.y = pack_bf16x2(acc[mt][nt][2], acc[mt][nt][3]);
        *(uint2*)&lOut[d * STR + n] = pk;
      }
    __syncthreads();
    const int row0 = by * BM;
    const int bidx = row0 >> 11, n0 = row0 & 2047;
    const int col0 = bx * BN;
    constexpr int CPR = BM / 32;                  // 32-el chunks per d-row
    constexpr int NITER = (BN * CPR) / 256;
#pragma unroll
    for (int it = 0; it < NITER; ++it) {
      const int idx = it * 256 + t;
      const int d = idx / CPR, off = (idx % CPR) * 32;
      const bf16* srcp = &lOut[d * STR + off];
      bf16* g = (bf16*)C + ((size_t)(bidx << 10) + col0 + d) * 2048 + n0 + off;
#pragma unroll
      for (int j = 0; j < 4; ++j)
        *(bf16x8*)(g + j * 8) = *(const bf16x8*)(srcp + j * 8);
    }
  } else {
    const int row_base = by * BM + wy * (BM / 2);
    const int col_base = bx * BN + wx * (BN / 2);
#pragma unroll
    for (int mt = 0; mt < MT; ++mt)
#pragma unroll
      for (int nt = 0; nt < NT; ++nt) {
        const int col = col_base + nt * 16 + l15;
        const float bb = has_bias ? bias[col] : 0.0f;
#pragma unroll
        for (int r = 0; r < 4; ++r) {
          const int row = row_base + mt * 16 + quad * 4 + r;
          float v = acc[mt][nt][r] + bb;
          if constexpr (std::is_same_v<TOUT, bf16>)
            C[(size_t)row * N + col] = __float2bfloat16(v);
          else
            C[(size_t)row * N + col] = v;
        }
      }
  }
}

// single-GEMM wrapper (P5) with flattened XCD swizzle (nwg % 8 == 0)
template <int BM, int BN, int TMODE, typename TOUT>
__global__ __launch_bounds__(256) void gemm_bt_kernel(
    const bf16* __restrict__ A, const bf16* __restrict__ Bt,
    const float* __restrict__ bias, TOUT* __restrict__ C,
    int N, int K, int has_bias)
{
  __shared__ __align__(16) bf16 smem[2 * (BM + BN) * 64];
  const int nwg = gridDim.x * gridDim.y;
  const int orig = blockIdx.y * gridDim.x + blockIdx.x;
  const int s = xcd_swz(orig, nwg);
  gemm_core<BM, BN, TMODE, TOUT>(A, Bt, bias, C, N, K, has_bias,
                                 s % gridDim.x, s / gridDim.x, smem);
}

// dual GEMM (P2): qk = keys_ln @ wqkT (512 blocks, 128x128) +
//                 vt = values_ln @ wvT (256 blocks, 128x128, TMODE1)
// NOTE: qk and vt must be DISJOINT workspace regions (concurrent in one
// dispatch) — enforced by the R14 workspace map. XCD swizzle per segment.
__global__ __launch_bounds__(256) void gemm_dual_kernel(
    const bf16* __restrict__ A0, const bf16* __restrict__ B0, bf16* __restrict__ C0,
    const bf16* __restrict__ A1, const bf16* __restrict__ B1, bf16* __restrict__ C1)
{
  __shared__ __align__(16) bf16 smem[2 * 256 * 64];  // 64KB -> 2 blocks/CU
  const int bid = blockIdx.x;
  if (bid < 512) {
    const int s = xcd_swz(bid, 512);
    gemm_core<128, 128, 0, bf16>(A0, B0, nullptr, C0, 2048, 1024, 0,
                                 s & 15, s >> 4, smem);
  } else {
    const int s = xcd_swz(bid - 512, 256);
    gemm_core<128, 128, 1, bf16>(A1, B1, nullptr, C1, 1024, 1024, 0,
                                 s & 7, s >> 3, smem);
  }
}

// ---------------- Flash attention (R17-exact): 2-subtile pipeline + in-register P + MFMA row sums ----------------
// P fully in-register via K-row permutation: LDS slot s (bits n1 n0 q1 q0
// r1 r0) holds global K row g(s) = (n1 q1 q0 n0 r1 r0) within each 64-row
// granule, so the QK^T C/D fragment, exp'd and packed, IS the 16x16x32 PV
// B-operand (col=l15, k=quad*8..+7). 16 iterations stage a 128-row K/V tile
// (two 64-row sub-tiles) per pinned-barrier pair with vmcnt(8). Row sums
// via ones-A MFMA. XCD-affine (b,h) grouping — flat 512-block grid,
// bh = (bid&7) + 8*(bid>>7), qt = (bid>>3)&15: all 16 q-tiles of one (b,h)
// on the same XCD under round-robin dispatch -> 512KB K/V panel stays
// L2-resident (verified: FETCH 73.8 -> 12.3MB). Best measured: 47.8us.
__global__ __launch_bounds__(256) void flash_kernel(
    const bf16* __restrict__ Q, const bf16* __restrict__ Km,
    const bf16* __restrict__ Vt, bf16* __restrict__ O)
{
  __shared__ __align__(16) bf16 smem[8192 + 16384 + 16384];  // 80KB; 2 blocks/CU (grid-limited anyway)
  bf16* lQ = smem;                  // 128x64
  bf16* lKb = smem + 8192;          // 2 x (2 x 64x64)
  bf16* lVb = smem + 8192 + 16384;  // 2 x (2 x 64x64)
  const int t = threadIdx.x;
  const int w = t >> 6, lane = t & 63, l15 = lane & 15, quad = lane >> 4;
  const int bid = blockIdx.x;
  const int qt = (bid >> 3) & 15;               // q-tile within (b,h)
  const int bh = (bid & 7) + ((bid >> 7) << 3); // XCD-affine (b,h) group
  const int b = bh >> 4, h = bh & 15;
  const int qrow0 = b * 2048 + qt * 128;
  const bf16* qbase = Q + (size_t)qrow0 * 1024 + h * 64;
  const bf16* kbase = Km + ((size_t)(b * 2048)) * 1024 + h * 64;
  const bf16* vbase = Vt + ((size_t)(b * 1024 + h * 64)) * 2048;

  const int sr0 = t >> 3, sc0 = ((t & 7) ^ (sr0 & 7)) << 3;
  const int sr1 = (256 + t) >> 3, sc1 = (((256 + t) & 7) ^ (sr1 & 7)) << 3;
  // K-row permutation g(s): (n1 n0 q1 q0 r1 r0) -> (n1 q1 q0 n0 r1 r0)
  const int gr0 = (sr0 & 0x23) | ((sr0 & 0x0C) << 1) | ((sr0 & 0x10) >> 2);
  const int gr1 = (sr1 & 0x23) | ((sr1 & 0x0C) << 1) | ((sr1 & 0x10) >> 2);
  const bf16* kp0 = kbase + gr0 * 1024 + sc0;
  const bf16* kp1 = kbase + gr1 * 1024 + sc1;
  const bf16* vp0 = vbase + sr0 * 2048 + sc0;
  const bf16* vp1 = vbase + sr1 * 2048 + sc1;

  // stage one 64-row K sub-tile (rows kro..+63) and 64-col V sub-tile into dst
  auto stage_kv = [&](bf16* kdst, bf16* vdst, int kro, int vco) {
    const int ko = kro << 10;  // kro * 1024
    gl_lds16(kp0 + ko, kdst + t * 8);
    gl_lds16(kp1 + ko, kdst + (256 + t) * 8);
    gl_lds16(vp0 + vco, vdst + t * 8);
    gl_lds16(vp1 + vco, vdst + (256 + t) * 8);
  };

  // prologue: stage Q (4) + K/V tile 0 (8: two sub-tiles)
#pragma unroll
  for (int i = 0; i < 4; ++i) {
    int s = i * 256 + t;
    int row = s >> 3, c = (s & 7) ^ (row & 7);
    gl_lds16(qbase + (size_t)row * 1024 + (c << 3), lQ + s * 8);
  }
  stage_kv(lKb, lVb, 0, 0);
  stage_kv(lKb + 4096, lVb + 4096, 64, 64);
  asm volatile("s_waitcnt vmcnt(8)" ::: "memory");  // Q done (in-order); tile0 in flight
  barrier_pinned();

  const int sw = (quad ^ (l15 & 7)) << 3;
  bf16x8 qf[2][2];
#pragma unroll
  for (int mset = 0; mset < 2; ++mset) {
    const int row = w * 32 + mset * 16 + l15;
    qf[mset][0] = *(const bf16x8*)&lQ[row * 64 + sw];
    qf[mset][1] = *(const bf16x8*)&lQ[row * 64 + (sw ^ 32)];
  }

  f32x4 o_acc[4][2] = {};   // [dt][mset]: O^T row d = dt*16+quad*4+r, col m = mset*16+l15
  f32x4 s_acc[2] = {};      // ones-MFMA row sums (all rows identical per lane col)
  const short ONEB = (short)0x3F80;  // bf16 1.0
  const bf16x8 ones = {ONEB, ONEB, ONEB, ONEB, ONEB, ONEB, ONEB, ONEB};

  for (int kt = 0; kt < 16; ++kt) {
    const int cur = kt & 1;
    bf16* lK = lKb + cur * 8192;
    bf16* lV = lVb + cur * 8192;
    bf16* lKn = lKb + (cur ^ 1) * 8192;
    bf16* lVn = lVb + (cur ^ 1) * 8192;

    barrier_pinned();  // all waves done reading buf cur^1
    {
      const int ktn = (kt + 1) & 15;  // wrap: restage tile 0 into dead buf
      const int kro = ktn << 7;       // ktn*128 K-rows
      const int vco = ktn << 7;       // ktn*128 V-cols
      stage_kv(lKn, lVn, kro, vco);
      stage_kv(lKn + 4096, lVn + 4096, kro + 64, vco + 64);
    }
    asm volatile("s_waitcnt vmcnt(8)" ::: "memory");  // current tile landed; next in flight
    barrier_pinned();  // tile kt visible to all waves; sub-tile reads pinned below

#pragma unroll
    for (int sub = 0; sub < 2; ++sub) {
      bf16* lKs = lK + sub * 4096;
      bf16* lVs = lV + sub * 4096;

      bf16x8 kf[4][2];
#pragma unroll
      for (int nt = 0; nt < 4; ++nt) {
        kf[nt][0] = *(const bf16x8*)&lKs[(nt * 16 + l15) * 64 + sw];
        kf[nt][1] = *(const bf16x8*)&lKs[(nt * 16 + l15) * 64 + (sw ^ 32)];
      }

      // S^T (log2-domain) + v_exp + truncating pack straight into B-operand regs
      bf16x8 pa[2][2];
#pragma unroll
      for (int mset = 0; mset < 2; ++mset) {
#pragma unroll
        for (int half = 0; half < 2; ++half) {
          f32x4 z0 = {}, z1 = {};
          z0 = MFMA_BF16(kf[2 * half + 0][0], qf[mset][0], z0);
          z0 = MFMA_BF16(kf[2 * half + 0][1], qf[mset][1], z0);
          z1 = MFMA_BF16(kf[2 * half + 1][0], qf[mset][0], z1);
          z1 = MFMA_BF16(kf[2 * half + 1][1], qf[mset][1], z1);
          f32x4 p0, p1;
#pragma unroll
          for (int r = 0; r < 4; ++r) {
            p0[r] = __builtin_amdgcn_exp2f(z0[r]);
            p1[r] = __builtin_amdgcn_exp2f(z1[r]);
          }
          union { unsigned u[4]; bf16x8 v; } cv;
          cv.u[0] = pack_bf16x2_trunc(p0[0], p0[1]);
          cv.u[1] = pack_bf16x2_trunc(p0[2], p0[3]);
          cv.u[2] = pack_bf16x2_trunc(p1[0], p1[1]);
          cv.u[3] = pack_bf16x2_trunc(p1[2], p1[3]);
          pa[mset][half] = cv.v;
        }
      }

      bf16x8 vf[4][2];
#pragma unroll
      for (int dt = 0; dt < 4; ++dt) {
        vf[dt][0] = *(const bf16x8*)&lVs[(dt * 16 + l15) * 64 + sw];
        vf[dt][1] = *(const bf16x8*)&lVs[(dt * 16 + l15) * 64 + (sw ^ 32)];
      }

      __builtin_amdgcn_s_setprio(1);
#pragma unroll
      for (int mset = 0; mset < 2; ++mset) {
        s_acc[mset] = MFMA_BF16(ones, pa[mset][0], s_acc[mset]);
        s_acc[mset] = MFMA_BF16(ones, pa[mset][1], s_acc[mset]);
#pragma unroll
        for (int dt = 0; dt < 4; ++dt) {
          o_acc[dt][mset] = MFMA_BF16(vf[dt][0], pa[mset][0], o_acc[dt][mset]);
          o_acc[dt][mset] = MFMA_BF16(vf[dt][1], pa[mset][1], o_acc[dt][mset]);
        }
      }
      __builtin_amdgcn_s_setprio(0);
    }
  }

  // epilogue: divide + store O^T fragments (row sum already complete per lane)
#pragma unroll
  for (int mset = 0; mset < 2; ++mset) {
    const float inv = 1.0f / s_acc[mset][0];
    const int m = qrow0 + w * 32 + mset * 16 + l15;
#pragma unroll
    for (int dt = 0; dt < 4; ++dt) {
      uint2 ok;
      ok.x = pack_bf16x2(o_acc[dt][mset][0] * inv, o_acc[dt][mset][1] * inv);
      ok.y = pack_bf16x2(o_acc[dt][mset][2] * inv, o_acc[dt][mset][3] * inv);
      *(uint2*)&O[(size_t)m * 1024 + h * 64 + dt * 16 + quad * 4] = ok;
    }
  }
}

extern "C" void kernel_launch(void* const* d_in, const int* in_sizes, int n_in,
                              void* d_out, int out_size, void* d_ws, size_t ws_size,
                              hipStream_t stream)
{
  (void)in_sizes; (void)n_in; (void)out_size; (void)ws_size;
  const float* keys   = (const float*)d_in[0];
  const float* values = (const float*)d_in[1];
  const float* qk_g   = (const float*)d_in[2];
  const float* qk_b   = (const float*)d_in[3];
  const float* val_g  = (const float*)d_in[4];
  const float* val_b  = (const float*)d_in[5];
  const float* key_g  = (const float*)d_in[6];
  const float* key_b  = (const float*)d_in[7];
  const float* qry_g  = (const float*)d_in[8];
  const float* qry_b  = (const float*)d_in[9];
  const float* w_qk   = (const float*)d_in[10];
  const float* w_v    = (const float*)d_in[11];
  const float* w_out  = (const float*)d_in[12];
  const float* b_out  = (const float*)d_in[13];
  float* out = (float*)d_out;

  const float CEXP = 0.03125f * 1.44269504f;  // ID^-0.5 * log2(e), folded into q-LN

  // R14 workspace map (48MB) — lifetime-disjoint under the merged schedule.
  // P1: prep (writes keys_ln, values_ln, weights)
  // P2: dual GEMM (reads keys_ln/values_ln/wqkT/wvT; writes qk, vt — DISJOINT)
  // P3: q/k LN (reads qk; writes qln over keys_ln, kln over values_ln — both dead)
  // P4: flash (reads qln/kln/vt; writes attn over qk[0:8MB] — qk dead)
  // P5: out GEMM (reads attn/woutT; writes d_out)
  char* ws = (char*)d_ws;
  const size_t MB = 1024 * 1024;
  bf16* keys_ln   = (bf16*)(ws + 0);        // 8MB   P1w, P2r
  bf16* values_ln = (bf16*)(ws + 8 * MB);   // 8MB   P1w, P2r
  bf16* qk        = (bf16*)(ws + 16 * MB);  // 16MB  P2w, P3r
  bf16* vt        = (bf16*)(ws + 32 * MB);  // 8MB   P2w, P4r
  bf16* qln       = (bf16*)(ws + 0);        // 8MB   P3w, P4r (reuses keys_ln)
  bf16* kln       = (bf16*)(ws + 8 * MB);   // 8MB   P3w, P4r (reuses values_ln)
  bf16* attn      = (bf16*)(ws + 16 * MB);  // 8MB   P4w, P5r (reuses qk)
  bf16* wqkT      = (bf16*)(ws + 40 * MB);  // 4MB   P1w, P2r
  bf16* wvT       = (bf16*)(ws + 44 * MB);  // 2MB   P1w, P2r
  bf16* woutT     = (bf16*)(ws + 46 * MB);  // 2MB   P1w, P5r

  // P1: input layernorms (wave-per-row, 2048 blocks) + weight transposes (1024 blocks)
  prep_kernel<<<dim3(3072), 256, 0, stream>>>(
      keys, values, qk_g, qk_b, val_g, val_b, keys_ln, values_ln,
      w_qk, wqkT, w_v, wvT, w_out, woutT);
  // P2: qk = keys_ln @ w_qk (512 blocks, 128x128) + vt transposed (256 blocks, 128x128)
  gemm_dual_kernel<<<dim3(768), 256, 0, stream>>>(
      keys_ln, wqkT, qk, values_ln, wvT, vt);
  // P3: q/k layernorms (wave-per-row, 2048 blocks); qln pre-scaled by CEXP
  ln2_kernel<bf16><<<dim3(2048), 256, 0, stream>>>(
      qk, qk + 1024, 2048, qry_g, qry_b, key_g, key_b, qln, kln, CEXP, 1.0f);
  // P4: flash attention -> attn (flat 512-block grid, XCD-affine bh grouping)
  flash_kernel<<<dim3(512), 256, 0, stream>>>(qln, kln, vt, attn);
  // P5: out = attn @ w_out + b_out (fp32 out), 128x64 tile, 512 blocks, 3 blocks/CU
  gemm_bt_kernel<128, 64, 0, float><<<dim3(16, 32), 256, 0, stream>>>(
      attn, woutT, b_out, out, 1024, 1024, 1);
}